// Round 5
// baseline (791.969 us; speedup 1.0000x reference)
//
#include <hip/hip_runtime.h>
#include <hip/hip_bf16.h>
#include <math.h>

#define B_ 4
#define R_ 1024
#define G_ 8
#define E_ 192
#define H_ 6
#define D_ 32
#define L_ 4
#define F_ 384
#define M_ (B_*R_*G_)              // 32768 rows
static const size_t NBUF = (size_t)M_ * E_;       // 6291456 elems
static const size_t WPL  = 8 * (size_t)E_ * E_ + 2 * (size_t)E_ * F_;  // bf16/layer

typedef __attribute__((ext_vector_type(8))) short bf16x8;
typedef __attribute__((ext_vector_type(8))) unsigned short u16x8;
typedef __attribute__((ext_vector_type(4))) float f32x4;

__device__ __forceinline__ float gelu_exact(float x) {
    return 0.5f * x * (1.0f + erff(x * 0.7071067811865475f));
}
__device__ __forceinline__ unsigned short f2bf(float f) {
    __hip_bfloat16 h = __float2bfloat16(f);
    return *(unsigned short*)&h;
}
__device__ __forceinline__ float bf2f(unsigned short h) {
    union { unsigned u; float f; } v; v.u = ((unsigned)h) << 16; return v.f;
}

// ---- one-shot: transpose+convert all weights to Wt[N][K] bf16.
// Scale folds: Wq1 *= 1/sqrt(D); Wq2 *= log2(e)/sqrt(D)  (attn2 runs in exp2 domain).
__global__ __launch_bounds__(256)
void k_convw_all(const float* __restrict__ Wq1, const float* __restrict__ Wk1,
                 const float* __restrict__ Wv1, const float* __restrict__ Wo1,
                 const float* __restrict__ Wq2, const float* __restrict__ Wk2,
                 const float* __restrict__ Wv2, const float* __restrict__ Wo2,
                 const float* __restrict__ W1,  const float* __restrict__ W2,
                 unsigned short* __restrict__ Wt)
{
    const int t = blockIdx.x;
    const int layer = t / 432;
    const int r = t % 432;
    const float* src; unsigned short* dst; int K, N; float scale = 1.f; int tile;
    if (r < 288) {
        const int w = r / 36; tile = r % 36; K = E_; N = E_;
        const float* tab[8] = {Wq1, Wk1, Wv1, Wo1, Wq2, Wk2, Wv2, Wo2};
        src = tab[w] + (size_t)layer * E_ * E_;
        dst = Wt + (size_t)layer * WPL + (size_t)w * E_ * E_;
        if (w == 0) scale = 0.17677669529663687f;                       // 1/sqrt(32)
        if (w == 4) scale = 0.17677669529663687f * 1.4426950408889634f; // log2e/sqrt(32)
    } else if (r < 360) {
        tile = r - 288; K = E_; N = F_;
        src = W1 + (size_t)layer * E_ * F_;
        dst = Wt + (size_t)layer * WPL + 8 * (size_t)E_ * E_;
    } else {
        tile = r - 360; K = F_; N = E_;
        src = W2 + (size_t)layer * E_ * F_;
        dst = Wt + (size_t)layer * WPL + 8 * (size_t)E_ * E_ + (size_t)E_ * F_;
    }
    const int ntx = N / 32;
    const int kb = (tile / ntx) * 32, nb = (tile % ntx) * 32;
    __shared__ float tl[32][33];
    const int tx = threadIdx.x & 31, ty = threadIdx.x >> 5;
    for (int i2 = 0; i2 < 32; i2 += 8)
        tl[ty + i2][tx] = src[(size_t)(kb + ty + i2) * N + nb + tx];
    __syncthreads();
    for (int i2 = 0; i2 < 32; i2 += 8)
        dst[(size_t)(nb + ty + i2) * K + kb + tx] = f2bf(tl[tx][ty + i2] * scale);
}

// ---- MFMA GEMM, tile 64 x 192, BK=32, 4 waves.
// EPI: 0 = store bf16 at [m][n0+n], ldc
//      1 = gelu -> bf16, ldc
//      2 = +res, row-RMS*g -> bf16, transpose X->XR    (grid.y must be 1)
//      3 = +res, row-RMS*g -> bf16, transpose XR->X
//      4 = +res, row-RMS*g -> f32, no transpose
//      5 = +res, row-RMS*g -> bf16, no transpose
template<bool ABF16, bool RESBF16, int EPI>
__global__ __launch_bounds__(256)
void k_gemm_mfma(const void* __restrict__ Ap, const unsigned short* __restrict__ Wt,
                 const void* __restrict__ Resp, const float* __restrict__ gvec,
                 void* __restrict__ Cp, int ldc, int K)
{
    __shared__ unsigned short As[64][40];
    __shared__ unsigned short Bs[192][40];
    __shared__ float ss_red[4][64];
    const int m0 = blockIdx.x * 64;
    const int n0 = blockIdx.y * 192;
    const int tid = threadIdx.x;
    const int w = tid >> 6, lane = tid & 63, l15 = lane & 15, g = lane >> 4;
    const int arow = tid >> 2, akoff = (tid & 3) << 3;
    f32x4 acc[4][3];
#pragma unroll
    for (int mt = 0; mt < 4; ++mt)
#pragma unroll
        for (int nt = 0; nt < 3; ++nt)
#pragma unroll
            for (int r2 = 0; r2 < 4; ++r2) acc[mt][nt][r2] = 0.f;
    const int nK = K >> 5;
    for (int kc = 0; kc < nK; ++kc) {
        const int k0 = kc << 5;
        u16x8 av;
        if (ABF16) {
            av = *(const u16x8*)((const unsigned short*)Ap + (size_t)(m0 + arow) * K + k0 + akoff);
        } else {
            const float* ap = (const float*)Ap + (size_t)(m0 + arow) * K + k0 + akoff;
            float4 x = *(const float4*)ap, y = *(const float4*)(ap + 4);
            av[0] = f2bf(x.x); av[1] = f2bf(x.y); av[2] = f2bf(x.z); av[3] = f2bf(x.w);
            av[4] = f2bf(y.x); av[5] = f2bf(y.y); av[6] = f2bf(y.z); av[7] = f2bf(y.w);
        }
        *(u16x8*)&As[arow][akoff] = av;
#pragma unroll
        for (int j = 0; j < 3; ++j) {
            const int v = tid + 256 * j;
            const int bn = v >> 2, bk = (v & 3) << 3;
            u16x8 bv = *(const u16x8*)(Wt + (size_t)(n0 + bn) * K + k0 + bk);
            *(u16x8*)&Bs[bn][bk] = bv;
        }
        __syncthreads();
        bf16x8 af[4], bfr[3];
#pragma unroll
        for (int mt = 0; mt < 4; ++mt) af[mt] = *(const bf16x8*)&As[mt * 16 + l15][g * 8];
#pragma unroll
        for (int nt = 0; nt < 3; ++nt) bfr[nt] = *(const bf16x8*)&Bs[w * 48 + nt * 16 + l15][g * 8];
#pragma unroll
        for (int mt = 0; mt < 4; ++mt)
#pragma unroll
            for (int nt = 0; nt < 3; ++nt)
                acc[mt][nt] = __builtin_amdgcn_mfma_f32_16x16x32_bf16(af[mt], bfr[nt], acc[mt][nt], 0, 0, 0);
        __syncthreads();
    }

    if (EPI <= 1) {
#pragma unroll
        for (int mt = 0; mt < 4; ++mt)
#pragma unroll
            for (int r2 = 0; r2 < 4; ++r2) {
                const int m = m0 + mt * 16 + g * 4 + r2;
#pragma unroll
                for (int nt = 0; nt < 3; ++nt) {
                    const int n = w * 48 + nt * 16 + l15;
                    float v = acc[mt][nt][r2];
                    if (EPI == 1) v = gelu_exact(v);
                    ((unsigned short*)Cp)[(size_t)m * ldc + n0 + n] = f2bf(v);
                }
            }
        return;
    }

    // --- residual + row RMSNorm epilogue (grid.y == 1, N == 192) ---
    float ssp[4][4];
#pragma unroll
    for (int mt = 0; mt < 4; ++mt)
#pragma unroll
        for (int r2 = 0; r2 < 4; ++r2) ssp[mt][r2] = 0.f;
#pragma unroll
    for (int mt = 0; mt < 4; ++mt)
#pragma unroll
        for (int r2 = 0; r2 < 4; ++r2) {
            const int m = m0 + mt * 16 + g * 4 + r2;
#pragma unroll
            for (int nt = 0; nt < 3; ++nt) {
                const int n = w * 48 + nt * 16 + l15;
                float rres = RESBF16 ? bf2f(((const unsigned short*)Resp)[(size_t)m * E_ + n])
                                     : ((const float*)Resp)[(size_t)m * E_ + n];
                float v = acc[mt][nt][r2] + rres;
                acc[mt][nt][r2] = v;
                ssp[mt][r2] += v * v;
            }
        }
#pragma unroll
    for (int off = 1; off < 16; off <<= 1)
#pragma unroll
        for (int mt = 0; mt < 4; ++mt)
#pragma unroll
            for (int r2 = 0; r2 < 4; ++r2)
                ssp[mt][r2] += __shfl_xor(ssp[mt][r2], off);
    if (l15 == 0) {
#pragma unroll
        for (int mt = 0; mt < 4; ++mt)
#pragma unroll
            for (int r2 = 0; r2 < 4; ++r2)
                ss_red[w][mt * 16 + g * 4 + r2] = ssp[mt][r2];
    }
    __syncthreads();
#pragma unroll
    for (int mt = 0; mt < 4; ++mt) {
#pragma unroll
        for (int r2 = 0; r2 < 4; ++r2) {
            const int lrow = mt * 16 + g * 4 + r2;
            const float ss = ss_red[0][lrow] + ss_red[1][lrow] + ss_red[2][lrow] + ss_red[3][lrow];
            const float inv = rsqrtf(ss * (1.0f / 192.0f) + 1.1920929e-07f);
            const int m = m0 + lrow;
            size_t orow;
            if (EPI == 2) {        // X -> XR
                const int b = m >> 13, rr = (m >> 3) & 1023, gg = m & 7;
                orow = (((size_t)b * G_ + gg) << 10) + rr;
            } else if (EPI == 3) { // XR -> X
                const int b = m >> 13, gg = (m >> 10) & 7, rr = m & 1023;
                orow = ((((size_t)b << 10) + rr) << 3) + gg;
            } else {
                orow = m;
            }
#pragma unroll
            for (int nt = 0; nt < 3; ++nt) {
                const int n = w * 48 + nt * 16 + l15;
                const float v = acc[mt][nt][r2] * inv * gvec[n];
                if (EPI == 4) ((float*)Cp)[orow * E_ + n] = v;
                else          ((unsigned short*)Cp)[orow * E_ + n] = f2bf(v);
            }
        }
    }
}

// ---- Feature-group attention. QKV fused buffer [M][576]: Q=0, K=+192, V=+384.
__global__ __launch_bounds__(256)
void k_attn1(const unsigned short* __restrict__ QKV, unsigned short* __restrict__ T)
{
    const int wave = blockIdx.x * 4 + (threadIdx.x >> 6);
    const int lane = threadIdx.x & 63;
    const int seq = wave / H_;
    const int h = wave % H_;
    const int i = lane >> 3, j = lane & 7;
    const unsigned short* qp = QKV + ((size_t)(seq * G_ + i)) * 576 + h * D_;
    const unsigned short* kp = QKV + ((size_t)(seq * G_ + j)) * 576 + 192 + h * D_;
    float s = 0.f;
#pragma unroll
    for (int d8 = 0; d8 < 4; ++d8) {
        u16x8 qv = *(const u16x8*)(qp + d8 * 8);
        u16x8 kv = *(const u16x8*)(kp + d8 * 8);
#pragma unroll
        for (int e = 0; e < 8; ++e) s += bf2f(qv[e]) * bf2f(kv[e]);
    }
    float mx = s;
#pragma unroll
    for (int off = 1; off < 8; off <<= 1) mx = fmaxf(mx, __shfl_xor(mx, off));
    float p = __expf(s - mx);
    float sum = p;
#pragma unroll
    for (int off = 1; off < 8; off <<= 1) sum += __shfl_xor(sum, off);
    p /= sum;
    const int base = lane & ~7;
    float o0 = 0.f, o1 = 0.f, o2 = 0.f, o3 = 0.f;
#pragma unroll
    for (int jj = 0; jj < 8; ++jj) {
        float pj = __shfl(p, base + jj);
        ushort4 vv = *(const ushort4*)(QKV + ((size_t)(seq * G_ + jj)) * 576 + 384 + h * D_ + j * 4);
        o0 += pj * bf2f(vv.x); o1 += pj * bf2f(vv.y);
        o2 += pj * bf2f(vv.z); o3 += pj * bf2f(vv.w);
    }
    ushort4 ov; ov.x = f2bf(o0); ov.y = f2bf(o1); ov.z = f2bf(o2); ov.w = f2bf(o3);
    *(ushort4*)(T + ((size_t)(seq * G_ + i)) * E_ + h * D_ + j * 4) = ov;
}

// ---- Row attention, MFMA flash, exp2 domain (log2e folded into Wq2).
// q-tile 128 per block (4 waves x 2 sub-tiles of 16 q): K/V staged once per
// chunk serves 2x the q-rows vs the 64-q version (staging+barriers halved).
// Grid 1536 = 6 blocks/CU. Swizzle keeps all 8 q-tiles of one (s,h) on one XCD.
__global__ __launch_bounds__(256)
void k_attn2(const unsigned short* __restrict__ QKV, unsigned short* __restrict__ T,
             const int* __restrict__ sep_ptr)
{
    __shared__ unsigned short K_lds[64][40];
    __shared__ unsigned short Vt_lds[32][74];
    __shared__ unsigned short P_lds[4][16][88];   // 176B rows: 16B-aligned, <=2-way banks

    const int sep = *sep_ptr;
    const int bid = blockIdx.x;
    const int sh = ((bid >> 6) << 3) | (bid & 7);   // same (s,h) => same XCD
    const int qtile = (bid >> 3) & 7;
    const int s = sh / H_, h = sh % H_;
    const int q0 = qtile * 128;

    const int tid = threadIdx.x;
    const int w = tid >> 6;
    const int lane = tid & 63;
    const int l15 = lane & 15;
    const int g = lane >> 4;

    u16x8 qf[2];
#pragma unroll
    for (int sub = 0; sub < 2; ++sub) {
        const int qrow = q0 + w * 32 + sub * 16 + l15;
        qf[sub] = *(const u16x8*)(QKV + ((size_t)s * R_ + qrow) * 576 + h * D_ + g * 8);
    }

    const bool lo = (q0 < sep);
    const bool hi = (q0 + 128 > sep);
    const int npass = (lo && hi) ? 2 : 1;
    const int nChunk = (sep + 63) >> 6;

    const int skey = tid >> 2;
    const int sg   = tid & 3;

    for (int pass = 0; pass < npass; ++pass) {
        const int hk = (pass == 0) ? (lo ? h : 0) : 0;
        const unsigned short* Kb = QKV + (size_t)s * R_ * 576 + 192 + hk * D_;
        const unsigned short* Vb = QKV + (size_t)s * R_ * 576 + 384 + hk * D_;

        float m[2], l[2];
        f32x4 o0[2], o1[2];
#pragma unroll
        for (int sub = 0; sub < 2; ++sub) {
            m[sub] = -1e30f; l[sub] = 0.f;
#pragma unroll
            for (int r = 0; r < 4; ++r) { o0[sub][r] = 0.f; o1[sub][r] = 0.f; }
        }

        for (int kc = 0; kc < nChunk; ++kc) {
            const int kbase = kc * 64;
            const bool full = (kbase + 64 <= sep);
            __syncthreads();
            *(u16x8*)&K_lds[skey][sg * 8] =
                *(const u16x8*)(Kb + (size_t)(kbase + skey) * 576 + sg * 8);
            {
                const int d0 = sg * 8;
                u16x8 vv = *(const u16x8*)(Vb + (size_t)(kbase + skey) * 576 + d0);
#pragma unroll
                for (int e = 0; e < 8; ++e) Vt_lds[d0 + e][skey] = vv[e];
            }
            __syncthreads();

#pragma unroll
            for (int sub = 0; sub < 2; ++sub) {
                f32x4 sc[4];
                const f32x4 zf = {0.f, 0.f, 0.f, 0.f};
#pragma unroll
                for (int t = 0; t < 4; ++t) {
                    bf16x8 a = *(const bf16x8*)&K_lds[t * 16 + l15][g * 8];
                    sc[t] = __builtin_amdgcn_mfma_f32_16x16x32_bf16(a, (bf16x8)qf[sub], zf, 0, 0, 0);
                }
                if (!full) {
#pragma unroll
                    for (int t = 0; t < 4; ++t)
#pragma unroll
                        for (int r = 0; r < 4; ++r)
                            if (kbase + t * 16 + g * 4 + r >= sep) sc[t][r] = -1e30f;
                }
                float mx = sc[0][0];
#pragma unroll
                for (int t = 0; t < 4; ++t)
#pragma unroll
                    for (int r = 0; r < 4; ++r) mx = fmaxf(mx, sc[t][r]);
                mx = fmaxf(mx, __shfl_xor(mx, 16));
                mx = fmaxf(mx, __shfl_xor(mx, 32));
                // defer-max: only rescale when some row grew by > 2^11
                if (!__all((int)(mx <= m[sub] + 11.0f))) {
                    const float mnew = fmaxf(m[sub], mx);
                    const float scl = exp2f(m[sub] - mnew);
                    l[sub] *= scl;
#pragma unroll
                    for (int r = 0; r < 4; ++r) { o0[sub][r] *= scl; o1[sub][r] *= scl; }
                    m[sub] = mnew;
                }
                float psum = 0.f;
#pragma unroll
                for (int t = 0; t < 4; ++t) {
                    ushort4 pw;
#pragma unroll
                    for (int r = 0; r < 4; ++r) {
                        const float p = exp2f(sc[t][r] - m[sub]);
                        psum += p;
                        ((unsigned short*)&pw)[r] = f2bf(p);
                    }
                    *(ushort4*)&P_lds[w][l15][t * 16 + g * 4] = pw;
                }
                psum += __shfl_xor(psum, 16);
                psum += __shfl_xor(psum, 32);
                l[sub] += psum;
#pragma unroll
                for (int ks = 0; ks < 2; ++ks) {
                    bf16x8 pb = *(const bf16x8*)&P_lds[w][l15][ks * 32 + g * 8];
                    bf16x8 va0 = *(const bf16x8*)&Vt_lds[l15][ks * 32 + g * 8];
                    bf16x8 va1 = *(const bf16x8*)&Vt_lds[16 + l15][ks * 32 + g * 8];
                    o0[sub] = __builtin_amdgcn_mfma_f32_16x16x32_bf16(va0, pb, o0[sub], 0, 0, 0);
                    o1[sub] = __builtin_amdgcn_mfma_f32_16x16x32_bf16(va1, pb, o1[sub], 0, 0, 0);
                }
            }
        }

#pragma unroll
        for (int sub = 0; sub < 2; ++sub) {
            const int qrow = q0 + w * 32 + sub * 16 + l15;
            const bool valid = (npass == 1) || (pass == 0 ? (qrow < sep) : (qrow >= sep));
            if (valid) {
                const float inv = 1.f / l[sub];
                unsigned short* tp = T + ((size_t)s * R_ + qrow) * E_ + h * D_;
                ushort4 v0, v1;
                v0.x = f2bf(o0[sub][0] * inv); v0.y = f2bf(o0[sub][1] * inv);
                v0.z = f2bf(o0[sub][2] * inv); v0.w = f2bf(o0[sub][3] * inv);
                v1.x = f2bf(o1[sub][0] * inv); v1.y = f2bf(o1[sub][1] * inv);
                v1.z = f2bf(o1[sub][2] * inv); v1.w = f2bf(o1[sub][3] * inv);
                *(ushort4*)(tp + g * 4)      = v0;
                *(ushort4*)(tp + 16 + g * 4) = v1;
            }
        }
    }
}

extern "C" void kernel_launch(void* const* d_in, const int* in_sizes, int n_in,
                              void* d_out, int out_size, void* d_ws, size_t ws_size,
                              hipStream_t stream) {
    const float* hidden = (const float*)d_in[0];
    const float* Wq1 = (const float*)d_in[1];
    const float* Wk1 = (const float*)d_in[2];
    const float* Wv1 = (const float*)d_in[3];
    const float* Wo1 = (const float*)d_in[4];
    const float* Wq2 = (const float*)d_in[5];
    const float* Wk2 = (const float*)d_in[6];
    const float* Wv2 = (const float*)d_in[7];
    const float* Wo2 = (const float*)d_in[8];
    const float* W1  = (const float*)d_in[9];
    const float* W2  = (const float*)d_in[10];
    const float* g1  = (const float*)d_in[11];
    const float* g2  = (const float*)d_in[12];
    const float* g3  = (const float*)d_in[13];
    const int*   sep = (const int*)d_in[14];

    float* Xout = (float*)d_out;                    // final f32 X-layout output
    unsigned short* ws = (unsigned short*)d_ws;
    unsigned short* QKVb = ws;                      // [M][576] bf16 (aliases H1 [M][384])
    unsigned short* Tb   = QKVb + (size_t)M_ * 576;
    unsigned short* Ynb  = Tb + NBUF;               // rms-g1 output, XR layout
    unsigned short* Xcb  = Ynb + NBUF;              // rms-g2 output, X layout
    unsigned short* Xb   = Xcb + NBUF;              // inter-layer residual (layers 0-2)
    unsigned short* Wt   = Xb + NBUF;
    unsigned short* H1b  = QKVb;

    const dim3 blk(256);
    const dim3 gQKV(M_ / 64, 3);
    const dim3 gW1(M_ / 64, 2);
    const dim3 g1x(M_ / 64, 1);
    const dim3 gA1((4096 * H_) / 4);
    const dim3 gA2(32 * H_ * 8);                    // (s,h) x 8 q-tiles of 128 rows
    const dim3 gR(M_ / 4);

    k_convw_all<<<dim3(432 * L_), blk, 0, stream>>>(Wq1, Wk1, Wv1, Wo1, Wq2, Wk2, Wv2, Wo2, W1, W2, Wt);

    for (int i = 0; i < L_; ++i) {
        unsigned short* wl = Wt + (size_t)i * WPL;
        const unsigned short* wqkv1 = wl;
        const unsigned short* wo1   = wl + 3 * (size_t)E_ * E_;
        const unsigned short* wqkv2 = wl + 4 * (size_t)E_ * E_;
        const unsigned short* wo2   = wl + 7 * (size_t)E_ * E_;
        const unsigned short* w1    = wl + 8 * (size_t)E_ * E_;
        const unsigned short* w2    = wl + 8 * (size_t)E_ * E_ + (size_t)E_ * F_;
        const float* g1i = g1 + (size_t)i * E_;
        const float* g2i = g2 + (size_t)i * E_;
        const float* g3i = g3 + (size_t)i * E_;

        // --- feature-group attention block ---
        if (i == 0)
            k_gemm_mfma<false, false, 0><<<gQKV, blk, 0, stream>>>(hidden, wqkv1, nullptr, nullptr, QKVb, 576, E_);
        else
            k_gemm_mfma<true, false, 0><<<gQKV, blk, 0, stream>>>(Xb, wqkv1, nullptr, nullptr, QKVb, 576, E_);
        k_attn1<<<gA1, blk, 0, stream>>>(QKVb, Tb);
        if (i == 0)
            k_gemm_mfma<true, false, 2><<<g1x, blk, 0, stream>>>(Tb, wo1, hidden, g1i, Ynb, E_, E_);
        else
            k_gemm_mfma<true, true, 2><<<g1x, blk, 0, stream>>>(Tb, wo1, Xb, g1i, Ynb, E_, E_);
        // --- row attention block ---
        k_gemm_mfma<true, false, 0><<<gQKV, blk, 0, stream>>>(Ynb, wqkv2, nullptr, nullptr, QKVb, 576, E_);
        k_attn2<<<gA2, blk, 0, stream>>>(QKVb, Tb, sep);
        k_gemm_mfma<true, true, 3><<<g1x, blk, 0, stream>>>(Tb, wo2, Ynb, g2i, Xcb, E_, E_);
        // --- MLP block ---
        k_gemm_mfma<true, false, 1><<<gW1, blk, 0, stream>>>(Xcb, w1, nullptr, nullptr, H1b, F_, E_);
        if (i == L_ - 1)
            k_gemm_mfma<true, true, 4><<<g1x, blk, 0, stream>>>(H1b, w2, Xcb, g3i, Xout, E_, F_);
        else
            k_gemm_mfma<true, true, 5><<<g1x, blk, 0, stream>>>(H1b, w2, Xcb, g3i, Xb, E_, F_);
    }
}

// Round 6
// 731.749 us; speedup vs baseline: 1.0823x; 1.0823x over previous
//
#include <hip/hip_runtime.h>
#include <hip/hip_bf16.h>
#include <math.h>

#define B_ 4
#define R_ 1024
#define G_ 8
#define E_ 192
#define H_ 6
#define D_ 32
#define L_ 4
#define F_ 384
#define M_ (B_*R_*G_)              // 32768 rows
static const size_t NBUF = (size_t)M_ * E_;       // 6291456 elems
static const size_t WPL  = 8 * (size_t)E_ * E_ + 2 * (size_t)E_ * F_;  // bf16/layer

typedef __attribute__((ext_vector_type(8))) short bf16x8;
typedef __attribute__((ext_vector_type(8))) unsigned short u16x8;
typedef __attribute__((ext_vector_type(4))) float f32x4;

__device__ __forceinline__ float gelu_exact(float x) {
    return 0.5f * x * (1.0f + erff(x * 0.7071067811865475f));
}
__device__ __forceinline__ unsigned short f2bf(float f) {
    __hip_bfloat16 h = __float2bfloat16(f);
    return *(unsigned short*)&h;
}
__device__ __forceinline__ float bf2f(unsigned short h) {
    union { unsigned u; float f; } v; v.u = ((unsigned)h) << 16; return v.f;
}

// ---- one-shot: transpose+convert all weights to Wt[N][K] bf16.
// Scale folds: Wq1 *= 1/sqrt(D); Wq2 *= log2(e)/sqrt(D)  (attn2 runs in exp2 domain).
__global__ __launch_bounds__(256)
void k_convw_all(const float* __restrict__ Wq1, const float* __restrict__ Wk1,
                 const float* __restrict__ Wv1, const float* __restrict__ Wo1,
                 const float* __restrict__ Wq2, const float* __restrict__ Wk2,
                 const float* __restrict__ Wv2, const float* __restrict__ Wo2,
                 const float* __restrict__ W1,  const float* __restrict__ W2,
                 unsigned short* __restrict__ Wt)
{
    const int t = blockIdx.x;
    const int layer = t / 432;
    const int r = t % 432;
    const float* src; unsigned short* dst; int K, N; float scale = 1.f; int tile;
    if (r < 288) {
        const int w = r / 36; tile = r % 36; K = E_; N = E_;
        const float* tab[8] = {Wq1, Wk1, Wv1, Wo1, Wq2, Wk2, Wv2, Wo2};
        src = tab[w] + (size_t)layer * E_ * E_;
        dst = Wt + (size_t)layer * WPL + (size_t)w * E_ * E_;
        if (w == 0) scale = 0.17677669529663687f;                       // 1/sqrt(32)
        if (w == 4) scale = 0.17677669529663687f * 1.4426950408889634f; // log2e/sqrt(32)
    } else if (r < 360) {
        tile = r - 288; K = E_; N = F_;
        src = W1 + (size_t)layer * E_ * F_;
        dst = Wt + (size_t)layer * WPL + 8 * (size_t)E_ * E_;
    } else {
        tile = r - 360; K = F_; N = E_;
        src = W2 + (size_t)layer * E_ * F_;
        dst = Wt + (size_t)layer * WPL + 8 * (size_t)E_ * E_ + (size_t)E_ * F_;
    }
    const int ntx = N / 32;
    const int kb = (tile / ntx) * 32, nb = (tile % ntx) * 32;
    __shared__ float tl[32][33];
    const int tx = threadIdx.x & 31, ty = threadIdx.x >> 5;
    for (int i2 = 0; i2 < 32; i2 += 8)
        tl[ty + i2][tx] = src[(size_t)(kb + ty + i2) * N + nb + tx];
    __syncthreads();
    for (int i2 = 0; i2 < 32; i2 += 8)
        dst[(size_t)(nb + ty + i2) * K + kb + tx] = f2bf(tl[tx][ty + i2] * scale);
}

// ---- MFMA GEMM, tile 64 x 192, BK=32, 4 waves, reg-prefetch pipeline:
// global loads for K-step kc+1 are issued right after the write barrier of kc,
// so L2/HBM latency hides under kc's ds_read + MFMA phase (T14 pattern).
// EPI: 0 = store bf16 at [m][n0+n], ldc
//      1 = gelu -> bf16, ldc
//      2 = +res, row-RMS*g -> bf16, transpose X->XR    (grid.y must be 1)
//      3 = +res, row-RMS*g -> bf16, transpose XR->X
//      4 = +res, row-RMS*g -> f32, no transpose
//      5 = +res, row-RMS*g -> bf16, no transpose
template<bool ABF16, bool RESBF16, int EPI>
__global__ __launch_bounds__(256)
void k_gemm_mfma(const void* __restrict__ Ap, const unsigned short* __restrict__ Wt,
                 const void* __restrict__ Resp, const float* __restrict__ gvec,
                 void* __restrict__ Cp, int ldc, int K)
{
    __shared__ unsigned short As[64][40];
    __shared__ unsigned short Bs[192][40];
    __shared__ float ss_red[4][64];
    const int m0 = blockIdx.x * 64;
    const int n0 = blockIdx.y * 192;
    const int tid = threadIdx.x;
    const int w = tid >> 6, lane = tid & 63, l15 = lane & 15, g = lane >> 4;
    const int arow = tid >> 2, akoff = (tid & 3) << 3;
    f32x4 acc[4][3];
#pragma unroll
    for (int mt = 0; mt < 4; ++mt)
#pragma unroll
        for (int nt = 0; nt < 3; ++nt)
#pragma unroll
            for (int r2 = 0; r2 < 4; ++r2) acc[mt][nt][r2] = 0.f;
    const int nK = K >> 5;

    float4 ax, ay; u16x8 av; u16x8 bv0, bv1, bv2;
    auto gload = [&](int k0) {
        if (ABF16) {
            av = *(const u16x8*)((const unsigned short*)Ap + (size_t)(m0 + arow) * K + k0 + akoff);
        } else {
            const float* ap = (const float*)Ap + (size_t)(m0 + arow) * K + k0 + akoff;
            ax = *(const float4*)ap; ay = *(const float4*)(ap + 4);
        }
        bv0 = *(const u16x8*)(Wt + (size_t)(n0 + arow      ) * K + k0 + akoff);
        bv1 = *(const u16x8*)(Wt + (size_t)(n0 + arow +  64) * K + k0 + akoff);
        bv2 = *(const u16x8*)(Wt + (size_t)(n0 + arow + 128) * K + k0 + akoff);
    };
    auto swrite = [&]() {
        u16x8 aw;
        if (ABF16) aw = av;
        else {
            aw[0] = f2bf(ax.x); aw[1] = f2bf(ax.y); aw[2] = f2bf(ax.z); aw[3] = f2bf(ax.w);
            aw[4] = f2bf(ay.x); aw[5] = f2bf(ay.y); aw[6] = f2bf(ay.z); aw[7] = f2bf(ay.w);
        }
        *(u16x8*)&As[arow][akoff] = aw;
        *(u16x8*)&Bs[arow][akoff] = bv0;
        *(u16x8*)&Bs[arow + 64][akoff] = bv1;
        *(u16x8*)&Bs[arow + 128][akoff] = bv2;
    };

    gload(0);
    for (int kc = 0; kc < nK; ++kc) {
        __syncthreads();          // prior K-step's reads complete
        swrite();                 // vmcnt wait lands here
        __syncthreads();
        if (kc + 1 < nK) gload((kc + 1) << 5);   // in flight during MFMA phase
        bf16x8 af[4], bfr[3];
#pragma unroll
        for (int mt = 0; mt < 4; ++mt) af[mt] = *(const bf16x8*)&As[mt * 16 + l15][g * 8];
#pragma unroll
        for (int nt = 0; nt < 3; ++nt) bfr[nt] = *(const bf16x8*)&Bs[w * 48 + nt * 16 + l15][g * 8];
#pragma unroll
        for (int mt = 0; mt < 4; ++mt)
#pragma unroll
            for (int nt = 0; nt < 3; ++nt)
                acc[mt][nt] = __builtin_amdgcn_mfma_f32_16x16x32_bf16(af[mt], bfr[nt], acc[mt][nt], 0, 0, 0);
    }

    if (EPI <= 1) {
#pragma unroll
        for (int mt = 0; mt < 4; ++mt)
#pragma unroll
            for (int r2 = 0; r2 < 4; ++r2) {
                const int m = m0 + mt * 16 + g * 4 + r2;
#pragma unroll
                for (int nt = 0; nt < 3; ++nt) {
                    const int n = w * 48 + nt * 16 + l15;
                    float v = acc[mt][nt][r2];
                    if (EPI == 1) v = gelu_exact(v);
                    ((unsigned short*)Cp)[(size_t)m * ldc + n0 + n] = f2bf(v);
                }
            }
        return;
    }

    // --- residual + row RMSNorm epilogue (grid.y == 1, N == 192) ---
    float ssp[4][4];
#pragma unroll
    for (int mt = 0; mt < 4; ++mt)
#pragma unroll
        for (int r2 = 0; r2 < 4; ++r2) ssp[mt][r2] = 0.f;
#pragma unroll
    for (int mt = 0; mt < 4; ++mt)
#pragma unroll
        for (int r2 = 0; r2 < 4; ++r2) {
            const int m = m0 + mt * 16 + g * 4 + r2;
#pragma unroll
            for (int nt = 0; nt < 3; ++nt) {
                const int n = w * 48 + nt * 16 + l15;
                float rres = RESBF16 ? bf2f(((const unsigned short*)Resp)[(size_t)m * E_ + n])
                                     : ((const float*)Resp)[(size_t)m * E_ + n];
                float v = acc[mt][nt][r2] + rres;
                acc[mt][nt][r2] = v;
                ssp[mt][r2] += v * v;
            }
        }
#pragma unroll
    for (int off = 1; off < 16; off <<= 1)
#pragma unroll
        for (int mt = 0; mt < 4; ++mt)
#pragma unroll
            for (int r2 = 0; r2 < 4; ++r2)
                ssp[mt][r2] += __shfl_xor(ssp[mt][r2], off);
    if (l15 == 0) {
#pragma unroll
        for (int mt = 0; mt < 4; ++mt)
#pragma unroll
            for (int r2 = 0; r2 < 4; ++r2)
                ss_red[w][mt * 16 + g * 4 + r2] = ssp[mt][r2];
    }
    __syncthreads();
#pragma unroll
    for (int mt = 0; mt < 4; ++mt) {
#pragma unroll
        for (int r2 = 0; r2 < 4; ++r2) {
            const int lrow = mt * 16 + g * 4 + r2;
            const float ss = ss_red[0][lrow] + ss_red[1][lrow] + ss_red[2][lrow] + ss_red[3][lrow];
            const float inv = rsqrtf(ss * (1.0f / 192.0f) + 1.1920929e-07f);
            const int m = m0 + lrow;
            size_t orow;
            if (EPI == 2) {        // X -> XR
                const int b = m >> 13, rr = (m >> 3) & 1023, gg = m & 7;
                orow = (((size_t)b * G_ + gg) << 10) + rr;
            } else if (EPI == 3) { // XR -> X
                const int b = m >> 13, gg = (m >> 10) & 7, rr = m & 1023;
                orow = ((((size_t)b << 10) + rr) << 3) + gg;
            } else {
                orow = m;
            }
#pragma unroll
            for (int nt = 0; nt < 3; ++nt) {
                const int n = w * 48 + nt * 16 + l15;
                const float v = acc[mt][nt][r2] * inv * gvec[n];
                if (EPI == 4) ((float*)Cp)[orow * E_ + n] = v;
                else          ((unsigned short*)Cp)[orow * E_ + n] = f2bf(v);
            }
        }
    }
}

// ---- Feature-group attention. QKV fused buffer [M][576]: Q=0, K=+192, V=+384.
__global__ __launch_bounds__(256)
void k_attn1(const unsigned short* __restrict__ QKV, unsigned short* __restrict__ T)
{
    const int wave = blockIdx.x * 4 + (threadIdx.x >> 6);
    const int lane = threadIdx.x & 63;
    const int seq = wave / H_;
    const int h = wave % H_;
    const int i = lane >> 3, j = lane & 7;
    const unsigned short* qp = QKV + ((size_t)(seq * G_ + i)) * 576 + h * D_;
    const unsigned short* kp = QKV + ((size_t)(seq * G_ + j)) * 576 + 192 + h * D_;
    float s = 0.f;
#pragma unroll
    for (int d8 = 0; d8 < 4; ++d8) {
        u16x8 qv = *(const u16x8*)(qp + d8 * 8);
        u16x8 kv = *(const u16x8*)(kp + d8 * 8);
#pragma unroll
        for (int e = 0; e < 8; ++e) s += bf2f(qv[e]) * bf2f(kv[e]);
    }
    float mx = s;
#pragma unroll
    for (int off = 1; off < 8; off <<= 1) mx = fmaxf(mx, __shfl_xor(mx, off));
    float p = __expf(s - mx);
    float sum = p;
#pragma unroll
    for (int off = 1; off < 8; off <<= 1) sum += __shfl_xor(sum, off);
    p /= sum;
    const int base = lane & ~7;
    float o0 = 0.f, o1 = 0.f, o2 = 0.f, o3 = 0.f;
#pragma unroll
    for (int jj = 0; jj < 8; ++jj) {
        float pj = __shfl(p, base + jj);
        ushort4 vv = *(const ushort4*)(QKV + ((size_t)(seq * G_ + jj)) * 576 + 384 + h * D_ + j * 4);
        o0 += pj * bf2f(vv.x); o1 += pj * bf2f(vv.y);
        o2 += pj * bf2f(vv.z); o3 += pj * bf2f(vv.w);
    }
    ushort4 ov; ov.x = f2bf(o0); ov.y = f2bf(o1); ov.z = f2bf(o2); ov.w = f2bf(o3);
    *(ushort4*)(T + ((size_t)(seq * G_ + i)) * E_ + h * D_ + j * 4) = ov;
}

// ---- Row attention, MFMA flash, exp2 domain (log2e folded into Wq2).
// 64-q blocks (R4 geometry: best occupancy) + reg-prefetch pipeline: next
// chunk's K/V global loads issue right after the stage barrier, hiding L2/HBM
// latency under the current chunk's QK/softmax/PV. Defer-max (THR=11, exp2
// domain) skips the O-rescale pass on most chunks.
__global__ __launch_bounds__(256)
void k_attn2(const unsigned short* __restrict__ QKV, unsigned short* __restrict__ T,
             const int* __restrict__ sep_ptr)
{
    __shared__ unsigned short K_lds[64][40];
    __shared__ unsigned short Vt_lds[32][74];
    __shared__ unsigned short P_lds[4][16][76];

    const int sep = *sep_ptr;
    const int bid = blockIdx.x;
    const int sh = ((bid >> 7) << 3) | (bid & 7);   // same (s,h) => same XCD
    const int qtile = (bid >> 3) & 15;
    const int s = sh / H_, h = sh % H_;
    const int q0 = qtile * 64;

    const int tid = threadIdx.x;
    const int w = tid >> 6;
    const int lane = tid & 63;
    const int l15 = lane & 15;
    const int g = lane >> 4;

    const int qrow = q0 + w * 16 + l15;
    u16x8 qf = *(const u16x8*)(QKV + ((size_t)s * R_ + qrow) * 576 + h * D_ + g * 8);

    const bool lo = (q0 < sep);
    const bool hi = (q0 + 64 > sep);
    const int npass = (lo && hi) ? 2 : 1;
    const int nChunk = (sep + 63) >> 6;

    const int skey = tid >> 2;
    const int sg   = tid & 3;

    for (int pass = 0; pass < npass; ++pass) {
        const int hk = (pass == 0) ? (lo ? h : 0) : 0;
        const unsigned short* Kb = QKV + (size_t)s * R_ * 576 + 192 + hk * D_;
        const unsigned short* Vb = QKV + (size_t)s * R_ * 576 + 384 + hk * D_;

        float mrun = -1e30f, lrun = 0.f;
        f32x4 o0 = {0.f, 0.f, 0.f, 0.f};
        f32x4 o1 = {0.f, 0.f, 0.f, 0.f};

        // prologue: prefetch chunk 0 into regs
        u16x8 kv_k = *(const u16x8*)(Kb + (size_t)skey * 576 + sg * 8);
        u16x8 kv_v = *(const u16x8*)(Vb + (size_t)skey * 576 + sg * 8);

        for (int kc = 0; kc < nChunk; ++kc) {
            const int kbase = kc * 64;
            const bool full = (kbase + 64 <= sep);
            __syncthreads();                      // prev chunk's LDS reads done
            *(u16x8*)&K_lds[skey][sg * 8] = kv_k; // vmcnt wait lands here
            {
                const int d0 = sg * 8;
#pragma unroll
                for (int e = 0; e < 8; ++e) Vt_lds[d0 + e][skey] = kv_v[e];
            }
            __syncthreads();
            if (kc + 1 < nChunk) {                // next chunk in flight under compute
                kv_k = *(const u16x8*)(Kb + (size_t)(kbase + 64 + skey) * 576 + sg * 8);
                kv_v = *(const u16x8*)(Vb + (size_t)(kbase + 64 + skey) * 576 + sg * 8);
            }

            f32x4 sc[4];
            const f32x4 zf = {0.f, 0.f, 0.f, 0.f};
#pragma unroll
            for (int t = 0; t < 4; ++t) {
                bf16x8 a = *(const bf16x8*)&K_lds[t * 16 + l15][g * 8];
                sc[t] = __builtin_amdgcn_mfma_f32_16x16x32_bf16(a, (bf16x8)qf, zf, 0, 0, 0);
            }
            if (!full) {
#pragma unroll
                for (int t = 0; t < 4; ++t)
#pragma unroll
                    for (int r = 0; r < 4; ++r)
                        if (kbase + t * 16 + g * 4 + r >= sep) sc[t][r] = -1e30f;
            }
            float mx = fmaxf(fmaxf(fmaxf(sc[0][0], sc[0][1]), fmaxf(sc[0][2], sc[0][3])),
                             fmaxf(fmaxf(sc[1][0], sc[1][1]), fmaxf(sc[1][2], sc[1][3])));
            mx = fmaxf(mx, fmaxf(fmaxf(fmaxf(sc[2][0], sc[2][1]), fmaxf(sc[2][2], sc[2][3])),
                                 fmaxf(fmaxf(sc[3][0], sc[3][1]), fmaxf(sc[3][2], sc[3][3]))));
            mx = fmaxf(mx, __shfl_xor(mx, 16));
            mx = fmaxf(mx, __shfl_xor(mx, 32));
            // defer-max: only rescale when some row grew by > 2^11
            if (!__all((int)(mx <= mrun + 11.0f))) {
                const float mnew = fmaxf(mrun, mx);
                const float scl = exp2f(mrun - mnew);
                lrun *= scl;
#pragma unroll
                for (int r = 0; r < 4; ++r) { o0[r] *= scl; o1[r] *= scl; }
                mrun = mnew;
            }
            float psum = 0.f;
#pragma unroll
            for (int t = 0; t < 4; ++t) {
                ushort4 pw;
#pragma unroll
                for (int r = 0; r < 4; ++r) {
                    const float p = exp2f(sc[t][r] - mrun);
                    psum += p;
                    ((unsigned short*)&pw)[r] = f2bf(p);
                }
                *(ushort4*)&P_lds[w][l15][t * 16 + g * 4] = pw;
            }
            psum += __shfl_xor(psum, 16);
            psum += __shfl_xor(psum, 32);
            lrun += psum;
#pragma unroll
            for (int ks = 0; ks < 2; ++ks) {
                bf16x8 pb = *(const bf16x8*)&P_lds[w][l15][ks * 32 + g * 8];
                bf16x8 va0 = *(const bf16x8*)&Vt_lds[l15][ks * 32 + g * 8];
                bf16x8 va1 = *(const bf16x8*)&Vt_lds[16 + l15][ks * 32 + g * 8];
                o0 = __builtin_amdgcn_mfma_f32_16x16x32_bf16(va0, pb, o0, 0, 0, 0);
                o1 = __builtin_amdgcn_mfma_f32_16x16x32_bf16(va1, pb, o1, 0, 0, 0);
            }
        }

        const bool valid = (npass == 1) || (pass == 0 ? (qrow < sep) : (qrow >= sep));
        if (valid) {
            const float inv = 1.f / lrun;
            unsigned short* tp = T + ((size_t)s * R_ + qrow) * E_ + h * D_;
            ushort4 v0, v1;
            v0.x = f2bf(o0[0] * inv); v0.y = f2bf(o0[1] * inv);
            v0.z = f2bf(o0[2] * inv); v0.w = f2bf(o0[3] * inv);
            v1.x = f2bf(o1[0] * inv); v1.y = f2bf(o1[1] * inv);
            v1.z = f2bf(o1[2] * inv); v1.w = f2bf(o1[3] * inv);
            *(ushort4*)(tp + g * 4)      = v0;
            *(ushort4*)(tp + 16 + g * 4) = v1;
        }
    }
}

extern "C" void kernel_launch(void* const* d_in, const int* in_sizes, int n_in,
                              void* d_out, int out_size, void* d_ws, size_t ws_size,
                              hipStream_t stream) {
    const float* hidden = (const float*)d_in[0];
    const float* Wq1 = (const float*)d_in[1];
    const float* Wk1 = (const float*)d_in[2];
    const float* Wv1 = (const float*)d_in[3];
    const float* Wo1 = (const float*)d_in[4];
    const float* Wq2 = (const float*)d_in[5];
    const float* Wk2 = (const float*)d_in[6];
    const float* Wv2 = (const float*)d_in[7];
    const float* Wo2 = (const float*)d_in[8];
    const float* W1  = (const float*)d_in[9];
    const float* W2  = (const float*)d_in[10];
    const float* g1  = (const float*)d_in[11];
    const float* g2  = (const float*)d_in[12];
    const float* g3  = (const float*)d_in[13];
    const int*   sep = (const int*)d_in[14];

    float* Xout = (float*)d_out;                    // final f32 X-layout output
    unsigned short* ws = (unsigned short*)d_ws;
    unsigned short* QKVb = ws;                      // [M][576] bf16 (aliases H1 [M][384])
    unsigned short* Tb   = QKVb + (size_t)M_ * 576;
    unsigned short* Ynb  = Tb + NBUF;               // rms-g1 output, XR layout
    unsigned short* Xcb  = Ynb + NBUF;              // rms-g2 output, X layout
    unsigned short* Xb   = Xcb + NBUF;              // inter-layer residual (layers 0-2)
    unsigned short* Wt   = Xb + NBUF;
    unsigned short* H1b  = QKVb;

    const dim3 blk(256);
    const dim3 gQKV(M_ / 64, 3);
    const dim3 gW1(M_ / 64, 2);
    const dim3 g1x(M_ / 64, 1);
    const dim3 gA1((4096 * H_) / 4);
    const dim3 gA2(32 * H_ * 16);                   // (s,h) x 16 q-tiles of 64 rows
    const dim3 gR(M_ / 4);

    k_convw_all<<<dim3(432 * L_), blk, 0, stream>>>(Wq1, Wk1, Wv1, Wo1, Wq2, Wk2, Wv2, Wo2, W1, W2, Wt);

    for (int i = 0; i < L_; ++i) {
        unsigned short* wl = Wt + (size_t)i * WPL;
        const unsigned short* wqkv1 = wl;
        const unsigned short* wo1   = wl + 3 * (size_t)E_ * E_;
        const unsigned short* wqkv2 = wl + 4 * (size_t)E_ * E_;
        const unsigned short* wo2   = wl + 7 * (size_t)E_ * E_;
        const unsigned short* w1    = wl + 8 * (size_t)E_ * E_;
        const unsigned short* w2    = wl + 8 * (size_t)E_ * E_ + (size_t)E_ * F_;
        const float* g1i = g1 + (size_t)i * E_;
        const float* g2i = g2 + (size_t)i * E_;
        const float* g3i = g3 + (size_t)i * E_;

        // --- feature-group attention block ---
        if (i == 0)
            k_gemm_mfma<false, false, 0><<<gQKV, blk, 0, stream>>>(hidden, wqkv1, nullptr, nullptr, QKVb, 576, E_);
        else
            k_gemm_mfma<true, false, 0><<<gQKV, blk, 0, stream>>>(Xb, wqkv1, nullptr, nullptr, QKVb, 576, E_);
        k_attn1<<<gA1, blk, 0, stream>>>(QKVb, Tb);
        if (i == 0)
            k_gemm_mfma<true, false, 2><<<g1x, blk, 0, stream>>>(Tb, wo1, hidden, g1i, Ynb, E_, E_);
        else
            k_gemm_mfma<true, true, 2><<<g1x, blk, 0, stream>>>(Tb, wo1, Xb, g1i, Ynb, E_, E_);
        // --- row attention block ---
        k_gemm_mfma<true, false, 0><<<gQKV, blk, 0, stream>>>(Ynb, wqkv2, nullptr, nullptr, QKVb, 576, E_);
        k_attn2<<<gA2, blk, 0, stream>>>(QKVb, Tb, sep);
        k_gemm_mfma<true, true, 3><<<g1x, blk, 0, stream>>>(Tb, wo2, Ynb, g2i, Xcb, E_, E_);
        // --- MLP block ---
        k_gemm_mfma<true, false, 1><<<gW1, blk, 0, stream>>>(Xcb, w1, nullptr, nullptr, H1b, F_, E_);
        if (i == L_ - 1)
            k_gemm_mfma<true, true, 4><<<g1x, blk, 0, stream>>>(H1b, w2, Xcb, g3i, Xout, E_, F_);
        else
            k_gemm_mfma<true, true, 5><<<g1x, blk, 0, stream>>>(H1b, w2, Xcb, g3i, Xb, E_, F_);
    }
}

// Round 7
// 730.470 us; speedup vs baseline: 1.0842x; 1.0018x over previous
//
#include <hip/hip_runtime.h>
#include <hip/hip_bf16.h>
#include <math.h>

#define B_ 4
#define R_ 1024
#define G_ 8
#define E_ 192
#define H_ 6
#define D_ 32
#define L_ 4
#define F_ 384
#define M_ (B_*R_*G_)              // 32768 rows
static const size_t NBUF = (size_t)M_ * E_;       // 6291456 elems
static const size_t WPL  = 8 * (size_t)E_ * E_ + 2 * (size_t)E_ * F_;  // bf16/layer

typedef __attribute__((ext_vector_type(8))) short bf16x8;
typedef __attribute__((ext_vector_type(8))) unsigned short u16x8;
typedef __attribute__((ext_vector_type(4))) float f32x4;

__device__ __forceinline__ float gelu_exact(float x) {
    return 0.5f * x * (1.0f + erff(x * 0.7071067811865475f));
}
__device__ __forceinline__ unsigned short f2bf(float f) {
    __hip_bfloat16 h = __float2bfloat16(f);
    return *(unsigned short*)&h;
}
__device__ __forceinline__ float bf2f(unsigned short h) {
    union { unsigned u; float f; } v; v.u = ((unsigned)h) << 16; return v.f;
}

// ---- one-shot: transpose+convert all weights to Wt[N][K] bf16.
// Scale folds: Wq1 *= 1/sqrt(D); Wq2 *= log2(e)/sqrt(D)  (attn2 runs in exp2 domain).
__global__ __launch_bounds__(256)
void k_convw_all(const float* __restrict__ Wq1, const float* __restrict__ Wk1,
                 const float* __restrict__ Wv1, const float* __restrict__ Wo1,
                 const float* __restrict__ Wq2, const float* __restrict__ Wk2,
                 const float* __restrict__ Wv2, const float* __restrict__ Wo2,
                 const float* __restrict__ W1,  const float* __restrict__ W2,
                 unsigned short* __restrict__ Wt)
{
    const int t = blockIdx.x;
    const int layer = t / 432;
    const int r = t % 432;
    const float* src; unsigned short* dst; int K, N; float scale = 1.f; int tile;
    if (r < 288) {
        const int w = r / 36; tile = r % 36; K = E_; N = E_;
        const float* tab[8] = {Wq1, Wk1, Wv1, Wo1, Wq2, Wk2, Wv2, Wo2};
        src = tab[w] + (size_t)layer * E_ * E_;
        dst = Wt + (size_t)layer * WPL + (size_t)w * E_ * E_;
        if (w == 0) scale = 0.17677669529663687f;                       // 1/sqrt(32)
        if (w == 4) scale = 0.17677669529663687f * 1.4426950408889634f; // log2e/sqrt(32)
    } else if (r < 360) {
        tile = r - 288; K = E_; N = F_;
        src = W1 + (size_t)layer * E_ * F_;
        dst = Wt + (size_t)layer * WPL + 8 * (size_t)E_ * E_;
    } else {
        tile = r - 360; K = F_; N = E_;
        src = W2 + (size_t)layer * E_ * F_;
        dst = Wt + (size_t)layer * WPL + 8 * (size_t)E_ * E_ + (size_t)E_ * F_;
    }
    const int ntx = N / 32;
    const int kb = (tile / ntx) * 32, nb = (tile % ntx) * 32;
    __shared__ float tl[32][33];
    const int tx = threadIdx.x & 31, ty = threadIdx.x >> 5;
    for (int i2 = 0; i2 < 32; i2 += 8)
        tl[ty + i2][tx] = src[(size_t)(kb + ty + i2) * N + nb + tx];
    __syncthreads();
    for (int i2 = 0; i2 < 32; i2 += 8)
        dst[(size_t)(nb + ty + i2) * K + kb + tx] = f2bf(tl[tx][ty + i2] * scale);
}

// ---- MFMA GEMM, tile 64 x 192, BK=32, 4 waves, reg-prefetch pipeline.
// EPI: 0 = store bf16 at [m][n0+n], ldc; 1 = gelu -> bf16, ldc.
template<bool ABF16, int EPI>
__global__ __launch_bounds__(256)
void k_gemm_mfma(const void* __restrict__ Ap, const unsigned short* __restrict__ Wt,
                 void* __restrict__ Cp, int ldc, int K)
{
    __shared__ unsigned short As[64][40];
    __shared__ unsigned short Bs[192][40];
    const int m0 = blockIdx.x * 64;
    const int n0 = blockIdx.y * 192;
    const int tid = threadIdx.x;
    const int w = tid >> 6, lane = tid & 63, l15 = lane & 15, g = lane >> 4;
    const int arow = tid >> 2, akoff = (tid & 3) << 3;
    f32x4 acc[4][3];
#pragma unroll
    for (int mt = 0; mt < 4; ++mt)
#pragma unroll
        for (int nt = 0; nt < 3; ++nt)
#pragma unroll
            for (int r2 = 0; r2 < 4; ++r2) acc[mt][nt][r2] = 0.f;
    const int nK = K >> 5;

    float4 ax, ay; u16x8 av; u16x8 bv0, bv1, bv2;
    auto gload = [&](int k0) {
        if (ABF16) {
            av = *(const u16x8*)((const unsigned short*)Ap + (size_t)(m0 + arow) * K + k0 + akoff);
        } else {
            const float* ap = (const float*)Ap + (size_t)(m0 + arow) * K + k0 + akoff;
            ax = *(const float4*)ap; ay = *(const float4*)(ap + 4);
        }
        bv0 = *(const u16x8*)(Wt + (size_t)(n0 + arow      ) * K + k0 + akoff);
        bv1 = *(const u16x8*)(Wt + (size_t)(n0 + arow +  64) * K + k0 + akoff);
        bv2 = *(const u16x8*)(Wt + (size_t)(n0 + arow + 128) * K + k0 + akoff);
    };
    auto swrite = [&]() {
        u16x8 aw;
        if (ABF16) aw = av;
        else {
            aw[0] = f2bf(ax.x); aw[1] = f2bf(ax.y); aw[2] = f2bf(ax.z); aw[3] = f2bf(ax.w);
            aw[4] = f2bf(ay.x); aw[5] = f2bf(ay.y); aw[6] = f2bf(ay.z); aw[7] = f2bf(ay.w);
        }
        *(u16x8*)&As[arow][akoff] = aw;
        *(u16x8*)&Bs[arow][akoff] = bv0;
        *(u16x8*)&Bs[arow + 64][akoff] = bv1;
        *(u16x8*)&Bs[arow + 128][akoff] = bv2;
    };

    gload(0);
    for (int kc = 0; kc < nK; ++kc) {
        __syncthreads();
        swrite();
        __syncthreads();
        if (kc + 1 < nK) gload((kc + 1) << 5);
        bf16x8 af[4], bfr[3];
#pragma unroll
        for (int mt = 0; mt < 4; ++mt) af[mt] = *(const bf16x8*)&As[mt * 16 + l15][g * 8];
#pragma unroll
        for (int nt = 0; nt < 3; ++nt) bfr[nt] = *(const bf16x8*)&Bs[w * 48 + nt * 16 + l15][g * 8];
#pragma unroll
        for (int mt = 0; mt < 4; ++mt)
#pragma unroll
            for (int nt = 0; nt < 3; ++nt)
                acc[mt][nt] = __builtin_amdgcn_mfma_f32_16x16x32_bf16(af[mt], bfr[nt], acc[mt][nt], 0, 0, 0);
    }

#pragma unroll
    for (int mt = 0; mt < 4; ++mt)
#pragma unroll
        for (int r2 = 0; r2 < 4; ++r2) {
            const int m = m0 + mt * 16 + g * 4 + r2;
#pragma unroll
            for (int nt = 0; nt < 3; ++nt) {
                const int n = w * 48 + nt * 16 + l15;
                float v = acc[mt][nt][r2];
                if (EPI == 1) v = gelu_exact(v);
                ((unsigned short*)Cp)[(size_t)m * ldc + n0 + n] = f2bf(v);
            }
        }
}

// ---- MFMA GEMM + residual + row-RMSNorm, tile 32 x 192, 4 waves, grid M/32.
// Wave w: m-tile (w&1), n-half (w>>1) of 96 cols (6 n-tiles). 4 blocks/CU.
// EPI: 2 = ->bf16, transpose X->XR; 3 = ->bf16, XR->X; 4 = ->f32; 5 = ->bf16.
template<bool RESBF16, int EPI>
__global__ __launch_bounds__(256)
void k_gemm_rms32(const unsigned short* __restrict__ Ap, const unsigned short* __restrict__ Wt,
                  const void* __restrict__ Resp, const float* __restrict__ gvec,
                  void* __restrict__ Cp, int K)
{
    __shared__ unsigned short As[32][40];
    __shared__ unsigned short Bs[192][40];
    __shared__ float ss_red[4][16];
    const int m0 = blockIdx.x * 32;
    const int tid = threadIdx.x;
    const int w = tid >> 6, lane = tid & 63, l15 = lane & 15, g = lane >> 4;
    const int mt = w & 1, nh = w >> 1;
    const int arow = tid >> 2, akoff = (tid & 3) << 3;
    f32x4 acc[6];
#pragma unroll
    for (int nt = 0; nt < 6; ++nt)
#pragma unroll
        for (int r2 = 0; r2 < 4; ++r2) acc[nt][r2] = 0.f;
    const int nK = K >> 5;

    u16x8 av, bv0, bv1, bv2;
    auto gload = [&](int k0) {
        if (tid < 128)
            av = *(const u16x8*)(Ap + (size_t)(m0 + arow) * K + k0 + akoff);
        bv0 = *(const u16x8*)(Wt + (size_t)(arow      ) * K + k0 + akoff);
        bv1 = *(const u16x8*)(Wt + (size_t)(arow +  64) * K + k0 + akoff);
        bv2 = *(const u16x8*)(Wt + (size_t)(arow + 128) * K + k0 + akoff);
    };
    auto swrite = [&]() {
        if (tid < 128) *(u16x8*)&As[arow][akoff] = av;
        *(u16x8*)&Bs[arow][akoff] = bv0;
        *(u16x8*)&Bs[arow + 64][akoff] = bv1;
        *(u16x8*)&Bs[arow + 128][akoff] = bv2;
    };

    gload(0);
    for (int kc = 0; kc < nK; ++kc) {
        __syncthreads();
        swrite();
        __syncthreads();
        if (kc + 1 < nK) gload((kc + 1) << 5);
        bf16x8 af = *(const bf16x8*)&As[mt * 16 + l15][g * 8];
        bf16x8 bfr[6];
#pragma unroll
        for (int nt = 0; nt < 6; ++nt) bfr[nt] = *(const bf16x8*)&Bs[nh * 96 + nt * 16 + l15][g * 8];
#pragma unroll
        for (int nt = 0; nt < 6; ++nt)
            acc[nt] = __builtin_amdgcn_mfma_f32_16x16x32_bf16(af, bfr[nt], acc[nt], 0, 0, 0);
    }

    // residual add + sum-sq partials
    float ssp[4] = {0.f, 0.f, 0.f, 0.f};
#pragma unroll
    for (int r2 = 0; r2 < 4; ++r2) {
        const int m = m0 + mt * 16 + g * 4 + r2;
#pragma unroll
        for (int nt = 0; nt < 6; ++nt) {
            const int n = nh * 96 + nt * 16 + l15;
            float rres = RESBF16 ? bf2f(((const unsigned short*)Resp)[(size_t)m * E_ + n])
                                 : ((const float*)Resp)[(size_t)m * E_ + n];
            float v = acc[nt][r2] + rres;
            acc[nt][r2] = v;
            ssp[r2] += v * v;
        }
    }
#pragma unroll
    for (int off = 1; off < 16; off <<= 1)
#pragma unroll
        for (int r2 = 0; r2 < 4; ++r2)
            ssp[r2] += __shfl_xor(ssp[r2], off);
    if (l15 == 0) {
#pragma unroll
        for (int r2 = 0; r2 < 4; ++r2)
            ss_red[w][g * 4 + r2] = ssp[r2];
    }
    __syncthreads();
#pragma unroll
    for (int r2 = 0; r2 < 4; ++r2) {
        const int lr = g * 4 + r2;
        const float ss = ss_red[mt][lr] + ss_red[2 + mt][lr];
        const float inv = rsqrtf(ss * (1.0f / 192.0f) + 1.1920929e-07f);
        const int m = m0 + mt * 16 + lr;
        size_t orow;
        if (EPI == 2) {        // X -> XR
            const int b = m >> 13, rr = (m >> 3) & 1023, gg = m & 7;
            orow = (((size_t)b * G_ + gg) << 10) + rr;
        } else if (EPI == 3) { // XR -> X
            const int b = m >> 13, gg = (m >> 10) & 7, rr = m & 1023;
            orow = ((((size_t)b << 10) + rr) << 3) + gg;
        } else {
            orow = m;
        }
#pragma unroll
        for (int nt = 0; nt < 6; ++nt) {
            const int n = nh * 96 + nt * 16 + l15;
            const float v = acc[nt][r2] * inv * gvec[n];
            if (EPI == 4) ((float*)Cp)[orow * E_ + n] = v;
            else          ((unsigned short*)Cp)[orow * E_ + n] = f2bf(v);
        }
    }
}

// ---- Feature-group attention. QKV fused buffer [M][576]: Q=0, K=+192, V=+384.
__global__ __launch_bounds__(256)
void k_attn1(const unsigned short* __restrict__ QKV, unsigned short* __restrict__ T)
{
    const int wave = blockIdx.x * 4 + (threadIdx.x >> 6);
    const int lane = threadIdx.x & 63;
    const int seq = wave / H_;
    const int h = wave % H_;
    const int i = lane >> 3, j = lane & 7;
    const unsigned short* qp = QKV + ((size_t)(seq * G_ + i)) * 576 + h * D_;
    const unsigned short* kp = QKV + ((size_t)(seq * G_ + j)) * 576 + 192 + h * D_;
    float s = 0.f;
#pragma unroll
    for (int d8 = 0; d8 < 4; ++d8) {
        u16x8 qv = *(const u16x8*)(qp + d8 * 8);
        u16x8 kv = *(const u16x8*)(kp + d8 * 8);
#pragma unroll
        for (int e = 0; e < 8; ++e) s += bf2f(qv[e]) * bf2f(kv[e]);
    }
    float mx = s;
#pragma unroll
    for (int off = 1; off < 8; off <<= 1) mx = fmaxf(mx, __shfl_xor(mx, off));
    float p = __expf(s - mx);
    float sum = p;
#pragma unroll
    for (int off = 1; off < 8; off <<= 1) sum += __shfl_xor(sum, off);
    p /= sum;
    const int base = lane & ~7;
    float o0 = 0.f, o1 = 0.f, o2 = 0.f, o3 = 0.f;
#pragma unroll
    for (int jj = 0; jj < 8; ++jj) {
        float pj = __shfl(p, base + jj);
        ushort4 vv = *(const ushort4*)(QKV + ((size_t)(seq * G_ + jj)) * 576 + 384 + h * D_ + j * 4);
        o0 += pj * bf2f(vv.x); o1 += pj * bf2f(vv.y);
        o2 += pj * bf2f(vv.z); o3 += pj * bf2f(vv.w);
    }
    ushort4 ov; ov.x = f2bf(o0); ov.y = f2bf(o1); ov.z = f2bf(o2); ov.w = f2bf(o3);
    *(ushort4*)(T + ((size_t)(seq * G_ + i)) * E_ + h * D_ + j * 4) = ov;
}

// ---- Row attention, MFMA flash, exp2 domain (log2e folded into Wq2).
// 64-q blocks + reg prefetch. Softmax denominator via ones-row MFMA (o2) on
// the matrix pipe; defer-max (THR=11) skips O-rescale on most chunks; max3
// chains; setprio around MFMA clusters.
__global__ __launch_bounds__(256)
void k_attn2(const unsigned short* __restrict__ QKV, unsigned short* __restrict__ T,
             const int* __restrict__ sep_ptr)
{
    __shared__ unsigned short K_lds[64][40];
    __shared__ unsigned short Vt_lds[32][74];
    __shared__ unsigned short P_lds[4][16][76];

    const int sep = *sep_ptr;
    const int bid = blockIdx.x;
    const int sh = ((bid >> 7) << 3) | (bid & 7);   // same (s,h) => same XCD
    const int qtile = (bid >> 3) & 15;
    const int s = sh / H_, h = sh % H_;
    const int q0 = qtile * 64;

    const int tid = threadIdx.x;
    const int w = tid >> 6;
    const int lane = tid & 63;
    const int l15 = lane & 15;
    const int g = lane >> 4;

    const int qrow = q0 + w * 16 + l15;
    u16x8 qf = *(const u16x8*)(QKV + ((size_t)s * R_ + qrow) * 576 + h * D_ + g * 8);

    u16x8 onesu;
#pragma unroll
    for (int e = 0; e < 8; ++e) onesu[e] = 0x3F80;  // bf16 1.0
    const bf16x8 onesf = (bf16x8)onesu;

    const bool lo = (q0 < sep);
    const bool hi = (q0 + 64 > sep);
    const int npass = (lo && hi) ? 2 : 1;
    const int nChunk = (sep + 63) >> 6;

    const int skey = tid >> 2;
    const int sg   = tid & 3;

    for (int pass = 0; pass < npass; ++pass) {
        const int hk = (pass == 0) ? (lo ? h : 0) : 0;
        const unsigned short* Kb = QKV + (size_t)s * R_ * 576 + 192 + hk * D_;
        const unsigned short* Vb = QKV + (size_t)s * R_ * 576 + 384 + hk * D_;

        float mrun = -1e30f;
        f32x4 o0 = {0.f, 0.f, 0.f, 0.f};
        f32x4 o1 = {0.f, 0.f, 0.f, 0.f};
        f32x4 o2 = {0.f, 0.f, 0.f, 0.f};   // ones-row: running sum of P (denominator)

        // prologue: prefetch chunk 0 into regs
        u16x8 kv_k = *(const u16x8*)(Kb + (size_t)skey * 576 + sg * 8);
        u16x8 kv_v = *(const u16x8*)(Vb + (size_t)skey * 576 + sg * 8);

        for (int kc = 0; kc < nChunk; ++kc) {
            const int kbase = kc * 64;
            const bool full = (kbase + 64 <= sep);
            __syncthreads();
            *(u16x8*)&K_lds[skey][sg * 8] = kv_k;
            {
                const int d0 = sg * 8;
#pragma unroll
                for (int e = 0; e < 8; ++e) Vt_lds[d0 + e][skey] = kv_v[e];
            }
            __syncthreads();
            if (kc + 1 < nChunk) {
                kv_k = *(const u16x8*)(Kb + (size_t)(kbase + 64 + skey) * 576 + sg * 8);
                kv_v = *(const u16x8*)(Vb + (size_t)(kbase + 64 + skey) * 576 + sg * 8);
            }

            f32x4 sc[4];
            const f32x4 zf = {0.f, 0.f, 0.f, 0.f};
            __builtin_amdgcn_s_setprio(1);
#pragma unroll
            for (int t = 0; t < 4; ++t) {
                bf16x8 a = *(const bf16x8*)&K_lds[t * 16 + l15][g * 8];
                sc[t] = __builtin_amdgcn_mfma_f32_16x16x32_bf16(a, (bf16x8)qf, zf, 0, 0, 0);
            }
            __builtin_amdgcn_s_setprio(0);
            if (!full) {
#pragma unroll
                for (int t = 0; t < 4; ++t)
#pragma unroll
                    for (int r = 0; r < 4; ++r)
                        if (kbase + t * 16 + g * 4 + r >= sep) sc[t][r] = -1e30f;
            }
            // max over 16 values, max3-fusable triples
            float mx = fmaxf(fmaxf(sc[0][0], sc[0][1]), sc[0][2]);
            mx = fmaxf(fmaxf(sc[0][3], sc[1][0]), mx);
            mx = fmaxf(fmaxf(sc[1][1], sc[1][2]), mx);
            mx = fmaxf(fmaxf(sc[1][3], sc[2][0]), mx);
            mx = fmaxf(fmaxf(sc[2][1], sc[2][2]), mx);
            mx = fmaxf(fmaxf(sc[2][3], sc[3][0]), mx);
            mx = fmaxf(fmaxf(sc[3][1], sc[3][2]), mx);
            mx = fmaxf(mx, sc[3][3]);
            mx = fmaxf(mx, __shfl_xor(mx, 16));
            mx = fmaxf(mx, __shfl_xor(mx, 32));
            // defer-max: only rescale when some row grew by > 2^11
            if (!__all((int)(mx <= mrun + 11.0f))) {
                const float mnew = fmaxf(mrun, mx);
                const float scl = exp2f(mrun - mnew);
#pragma unroll
                for (int r = 0; r < 4; ++r) { o0[r] *= scl; o1[r] *= scl; o2[r] *= scl; }
                mrun = mnew;
            }
#pragma unroll
            for (int t = 0; t < 4; ++t) {
                ushort4 pw;
#pragma unroll
                for (int r = 0; r < 4; ++r) {
                    const float p = exp2f(sc[t][r] - mrun);
                    ((unsigned short*)&pw)[r] = f2bf(p);
                }
                *(ushort4*)&P_lds[w][l15][t * 16 + g * 4] = pw;
            }
            __builtin_amdgcn_s_setprio(1);
#pragma unroll
            for (int ks = 0; ks < 2; ++ks) {
                bf16x8 pb = *(const bf16x8*)&P_lds[w][l15][ks * 32 + g * 8];
                bf16x8 va0 = *(const bf16x8*)&Vt_lds[l15][ks * 32 + g * 8];
                bf16x8 va1 = *(const bf16x8*)&Vt_lds[16 + l15][ks * 32 + g * 8];
                o0 = __builtin_amdgcn_mfma_f32_16x16x32_bf16(va0, pb, o0, 0, 0, 0);
                o1 = __builtin_amdgcn_mfma_f32_16x16x32_bf16(va1, pb, o1, 0, 0, 0);
                o2 = __builtin_amdgcn_mfma_f32_16x16x32_bf16(onesf, pb, o2, 0, 0, 0);
            }
            __builtin_amdgcn_s_setprio(0);
        }

        const bool valid = (npass == 1) || (pass == 0 ? (qrow < sep) : (qrow >= sep));
        if (valid) {
            const float inv = 1.f / o2[0];   // all 4 components equal = sum_k P[q][k]
            unsigned short* tp = T + ((size_t)s * R_ + qrow) * E_ + h * D_;
            ushort4 v0, v1;
            v0.x = f2bf(o0[0] * inv); v0.y = f2bf(o0[1] * inv);
            v0.z = f2bf(o0[2] * inv); v0.w = f2bf(o0[3] * inv);
            v1.x = f2bf(o1[0] * inv); v1.y = f2bf(o1[1] * inv);
            v1.z = f2bf(o1[2] * inv); v1.w = f2bf(o1[3] * inv);
            *(ushort4*)(tp + g * 4)      = v0;
            *(ushort4*)(tp + 16 + g * 4) = v1;
        }
    }
}

extern "C" void kernel_launch(void* const* d_in, const int* in_sizes, int n_in,
                              void* d_out, int out_size, void* d_ws, size_t ws_size,
                              hipStream_t stream) {
    const float* hidden = (const float*)d_in[0];
    const float* Wq1 = (const float*)d_in[1];
    const float* Wk1 = (const float*)d_in[2];
    const float* Wv1 = (const float*)d_in[3];
    const float* Wo1 = (const float*)d_in[4];
    const float* Wq2 = (const float*)d_in[5];
    const float* Wk2 = (const float*)d_in[6];
    const float* Wv2 = (const float*)d_in[7];
    const float* Wo2 = (const float*)d_in[8];
    const float* W1  = (const float*)d_in[9];
    const float* W2  = (const float*)d_in[10];
    const float* g1  = (const float*)d_in[11];
    const float* g2  = (const float*)d_in[12];
    const float* g3  = (const float*)d_in[13];
    const int*   sep = (const int*)d_in[14];

    float* Xout = (float*)d_out;                    // final f32 X-layout output
    unsigned short* ws = (unsigned short*)d_ws;
    unsigned short* QKVb = ws;                      // [M][576] bf16 (aliases H1 [M][384])
    unsigned short* Tb   = QKVb + (size_t)M_ * 576;
    unsigned short* Ynb  = Tb + NBUF;               // rms-g1 output, XR layout
    unsigned short* Xcb  = Ynb + NBUF;              // rms-g2 output, X layout
    unsigned short* Xb   = Xcb + NBUF;              // inter-layer residual (layers 0-2)
    unsigned short* Wt   = Xb + NBUF;
    unsigned short* H1b  = QKVb;

    const dim3 blk(256);
    const dim3 gQKV(M_ / 64, 3);
    const dim3 gW1(M_ / 64, 2);
    const dim3 g32(M_ / 32);                        // rms-GEMM: 1024 blocks, 4/CU
    const dim3 gA1((4096 * H_) / 4);
    const dim3 gA2(32 * H_ * 16);

    k_convw_all<<<dim3(432 * L_), blk, 0, stream>>>(Wq1, Wk1, Wv1, Wo1, Wq2, Wk2, Wv2, Wo2, W1, W2, Wt);

    for (int i = 0; i < L_; ++i) {
        unsigned short* wl = Wt + (size_t)i * WPL;
        const unsigned short* wqkv1 = wl;
        const unsigned short* wo1   = wl + 3 * (size_t)E_ * E_;
        const unsigned short* wqkv2 = wl + 4 * (size_t)E_ * E_;
        const unsigned short* wo2   = wl + 7 * (size_t)E_ * E_;
        const unsigned short* w1    = wl + 8 * (size_t)E_ * E_;
        const unsigned short* w2    = wl + 8 * (size_t)E_ * E_ + (size_t)E_ * F_;
        const float* g1i = g1 + (size_t)i * E_;
        const float* g2i = g2 + (size_t)i * E_;
        const float* g3i = g3 + (size_t)i * E_;

        // --- feature-group attention block ---
        if (i == 0)
            k_gemm_mfma<false, 0><<<gQKV, blk, 0, stream>>>(hidden, wqkv1, QKVb, 576, E_);
        else
            k_gemm_mfma<true, 0><<<gQKV, blk, 0, stream>>>(Xb, wqkv1, QKVb, 576, E_);
        k_attn1<<<gA1, blk, 0, stream>>>(QKVb, Tb);
        if (i == 0)
            k_gemm_rms32<false, 2><<<g32, blk, 0, stream>>>(Tb, wo1, hidden, g1i, Ynb, E_);
        else
            k_gemm_rms32<true, 2><<<g32, blk, 0, stream>>>(Tb, wo1, Xb, g1i, Ynb, E_);
        // --- row attention block ---
        k_gemm_mfma<true, 0><<<gQKV, blk, 0, stream>>>(Ynb, wqkv2, QKVb, 576, E_);
        k_attn2<<<gA2, blk, 0, stream>>>(QKVb, Tb, sep);
        k_gemm_rms32<true, 3><<<g32, blk, 0, stream>>>(Tb, wo2, Ynb, g2i, Xcb, E_);
        // --- MLP block ---
        k_gemm_mfma<true, 1><<<gW1, blk, 0, stream>>>(Xcb, w1, H1b, F_, E_);
        if (i == L_ - 1)
            k_gemm_rms32<true, 4><<<g32, blk, 0, stream>>>(H1b, w2, Xcb, g3i, Xout, F_);
        else
            k_gemm_rms32<true, 5><<<g32, blk, 0, stream>>>(H1b, w2, Xcb, g3i, Xb, F_);
    }
}

// Round 8
// 683.113 us; speedup vs baseline: 1.1594x; 1.0693x over previous
//
#include <hip/hip_runtime.h>
#include <hip/hip_bf16.h>
#include <math.h>

#define B_ 4
#define R_ 1024
#define G_ 8
#define E_ 192
#define H_ 6
#define D_ 32
#define L_ 4
#define F_ 384
#define M_ (B_*R_*G_)              // 32768 rows
static const size_t NBUF = (size_t)M_ * E_;       // 6291456 elems
static const size_t WPL  = 8 * (size_t)E_ * E_ + 2 * (size_t)E_ * F_;  // bf16/layer

typedef __attribute__((ext_vector_type(8))) short bf16x8;
typedef __attribute__((ext_vector_type(8))) unsigned short u16x8;
typedef __attribute__((ext_vector_type(4))) float f32x4;

__device__ __forceinline__ float gelu_exact(float x) {
    return 0.5f * x * (1.0f + erff(x * 0.7071067811865475f));
}
__device__ __forceinline__ unsigned short f2bf(float f) {
    __hip_bfloat16 h = __float2bfloat16(f);
    return *(unsigned short*)&h;
}
__device__ __forceinline__ float bf2f(unsigned short h) {
    union { unsigned u; float f; } v; v.u = ((unsigned)h) << 16; return v.f;
}
__device__ __forceinline__ bf16x8 mk8(unsigned long long lo, unsigned long long hi) {
    union { unsigned long long q[2]; bf16x8 v; } u;
    u.q[0] = lo; u.q[1] = hi; return u.v;
}

// ---- one-shot: transpose+convert all weights to Wt[N][K] bf16.
// Scale folds: Wq1 *= 1/sqrt(D); Wq2 *= log2(e)/sqrt(D)  (attn2 runs in exp2 domain).
__global__ __launch_bounds__(256)
void k_convw_all(const float* __restrict__ Wq1, const float* __restrict__ Wk1,
                 const float* __restrict__ Wv1, const float* __restrict__ Wo1,
                 const float* __restrict__ Wq2, const float* __restrict__ Wk2,
                 const float* __restrict__ Wv2, const float* __restrict__ Wo2,
                 const float* __restrict__ W1,  const float* __restrict__ W2,
                 unsigned short* __restrict__ Wt)
{
    const int t = blockIdx.x;
    const int layer = t / 432;
    const int r = t % 432;
    const float* src; unsigned short* dst; int K, N; float scale = 1.f; int tile;
    if (r < 288) {
        const int w = r / 36; tile = r % 36; K = E_; N = E_;
        const float* tab[8] = {Wq1, Wk1, Wv1, Wo1, Wq2, Wk2, Wv2, Wo2};
        src = tab[w] + (size_t)layer * E_ * E_;
        dst = Wt + (size_t)layer * WPL + (size_t)w * E_ * E_;
        if (w == 0) scale = 0.17677669529663687f;                       // 1/sqrt(32)
        if (w == 4) scale = 0.17677669529663687f * 1.4426950408889634f; // log2e/sqrt(32)
    } else if (r < 360) {
        tile = r - 288; K = E_; N = F_;
        src = W1 + (size_t)layer * E_ * F_;
        dst = Wt + (size_t)layer * WPL + 8 * (size_t)E_ * E_;
    } else {
        tile = r - 360; K = F_; N = E_;
        src = W2 + (size_t)layer * E_ * F_;
        dst = Wt + (size_t)layer * WPL + 8 * (size_t)E_ * E_ + (size_t)E_ * F_;
    }
    const int ntx = N / 32;
    const int kb = (tile / ntx) * 32, nb = (tile % ntx) * 32;
    __shared__ float tl[32][33];
    const int tx = threadIdx.x & 31, ty = threadIdx.x >> 5;
    for (int i2 = 0; i2 < 32; i2 += 8)
        tl[ty + i2][tx] = src[(size_t)(kb + ty + i2) * N + nb + tx];
    __syncthreads();
    for (int i2 = 0; i2 < 32; i2 += 8)
        dst[(size_t)(nb + ty + i2) * K + kb + tx] = f2bf(tl[tx][ty + i2] * scale);
}

// ---- MFMA GEMM, tile 64 x 192, BK=32, 4 waves, reg-prefetch pipeline.
// EPI: 0 = store bf16 at [m][n0+n], ldc; 1 = gelu -> bf16, ldc.
template<bool ABF16, int EPI>
__global__ __launch_bounds__(256)
void k_gemm_mfma(const void* __restrict__ Ap, const unsigned short* __restrict__ Wt,
                 void* __restrict__ Cp, int ldc, int K)
{
    __shared__ unsigned short As[64][40];
    __shared__ unsigned short Bs[192][40];
    const int m0 = blockIdx.x * 64;
    const int n0 = blockIdx.y * 192;
    const int tid = threadIdx.x;
    const int w = tid >> 6, lane = tid & 63, l15 = lane & 15, g = lane >> 4;
    const int arow = tid >> 2, akoff = (tid & 3) << 3;
    f32x4 acc[4][3];
#pragma unroll
    for (int mt = 0; mt < 4; ++mt)
#pragma unroll
        for (int nt = 0; nt < 3; ++nt)
#pragma unroll
            for (int r2 = 0; r2 < 4; ++r2) acc[mt][nt][r2] = 0.f;
    const int nK = K >> 5;

    float4 ax, ay; u16x8 av; u16x8 bv0, bv1, bv2;
    auto gload = [&](int k0) {
        if (ABF16) {
            av = *(const u16x8*)((const unsigned short*)Ap + (size_t)(m0 + arow) * K + k0 + akoff);
        } else {
            const float* ap = (const float*)Ap + (size_t)(m0 + arow) * K + k0 + akoff;
            ax = *(const float4*)ap; ay = *(const float4*)(ap + 4);
        }
        bv0 = *(const u16x8*)(Wt + (size_t)(n0 + arow      ) * K + k0 + akoff);
        bv1 = *(const u16x8*)(Wt + (size_t)(n0 + arow +  64) * K + k0 + akoff);
        bv2 = *(const u16x8*)(Wt + (size_t)(n0 + arow + 128) * K + k0 + akoff);
    };
    auto swrite = [&]() {
        u16x8 aw;
        if (ABF16) aw = av;
        else {
            aw[0] = f2bf(ax.x); aw[1] = f2bf(ax.y); aw[2] = f2bf(ax.z); aw[3] = f2bf(ax.w);
            aw[4] = f2bf(ay.x); aw[5] = f2bf(ay.y); aw[6] = f2bf(ay.z); aw[7] = f2bf(ay.w);
        }
        *(u16x8*)&As[arow][akoff] = aw;
        *(u16x8*)&Bs[arow][akoff] = bv0;
        *(u16x8*)&Bs[arow + 64][akoff] = bv1;
        *(u16x8*)&Bs[arow + 128][akoff] = bv2;
    };

    gload(0);
    for (int kc = 0; kc < nK; ++kc) {
        __syncthreads();
        swrite();
        __syncthreads();
        if (kc + 1 < nK) gload((kc + 1) << 5);
        bf16x8 af[4], bfr[3];
#pragma unroll
        for (int mt = 0; mt < 4; ++mt) af[mt] = *(const bf16x8*)&As[mt * 16 + l15][g * 8];
#pragma unroll
        for (int nt = 0; nt < 3; ++nt) bfr[nt] = *(const bf16x8*)&Bs[w * 48 + nt * 16 + l15][g * 8];
#pragma unroll
        for (int mt = 0; mt < 4; ++mt)
#pragma unroll
            for (int nt = 0; nt < 3; ++nt)
                acc[mt][nt] = __builtin_amdgcn_mfma_f32_16x16x32_bf16(af[mt], bfr[nt], acc[mt][nt], 0, 0, 0);
    }

#pragma unroll
    for (int mt = 0; mt < 4; ++mt)
#pragma unroll
        for (int r2 = 0; r2 < 4; ++r2) {
            const int m = m0 + mt * 16 + g * 4 + r2;
#pragma unroll
            for (int nt = 0; nt < 3; ++nt) {
                const int n = w * 48 + nt * 16 + l15;
                float v = acc[mt][nt][r2];
                if (EPI == 1) v = gelu_exact(v);
                ((unsigned short*)Cp)[(size_t)m * ldc + n0 + n] = f2bf(v);
            }
        }
}

// ---- MFMA GEMM + residual + row-RMSNorm, tile 32 x 192, 4 waves, grid M/32.
// EPI: 2 = ->bf16, transpose X->XR; 3 = ->bf16, XR->X; 4 = ->f32; 5 = ->bf16.
template<bool RESBF16, int EPI>
__global__ __launch_bounds__(256)
void k_gemm_rms32(const unsigned short* __restrict__ Ap, const unsigned short* __restrict__ Wt,
                  const void* __restrict__ Resp, const float* __restrict__ gvec,
                  void* __restrict__ Cp, int K)
{
    __shared__ unsigned short As[32][40];
    __shared__ unsigned short Bs[192][40];
    __shared__ float ss_red[4][16];
    const int m0 = blockIdx.x * 32;
    const int tid = threadIdx.x;
    const int w = tid >> 6, lane = tid & 63, l15 = lane & 15, g = lane >> 4;
    const int mt = w & 1, nh = w >> 1;
    const int arow = tid >> 2, akoff = (tid & 3) << 3;
    f32x4 acc[6];
#pragma unroll
    for (int nt = 0; nt < 6; ++nt)
#pragma unroll
        for (int r2 = 0; r2 < 4; ++r2) acc[nt][r2] = 0.f;
    const int nK = K >> 5;

    u16x8 av, bv0, bv1, bv2;
    auto gload = [&](int k0) {
        if (tid < 128)
            av = *(const u16x8*)(Ap + (size_t)(m0 + arow) * K + k0 + akoff);
        bv0 = *(const u16x8*)(Wt + (size_t)(arow      ) * K + k0 + akoff);
        bv1 = *(const u16x8*)(Wt + (size_t)(arow +  64) * K + k0 + akoff);
        bv2 = *(const u16x8*)(Wt + (size_t)(arow + 128) * K + k0 + akoff);
    };
    auto swrite = [&]() {
        if (tid < 128) *(u16x8*)&As[arow][akoff] = av;
        *(u16x8*)&Bs[arow][akoff] = bv0;
        *(u16x8*)&Bs[arow + 64][akoff] = bv1;
        *(u16x8*)&Bs[arow + 128][akoff] = bv2;
    };

    gload(0);
    for (int kc = 0; kc < nK; ++kc) {
        __syncthreads();
        swrite();
        __syncthreads();
        if (kc + 1 < nK) gload((kc + 1) << 5);
        bf16x8 af = *(const bf16x8*)&As[mt * 16 + l15][g * 8];
        bf16x8 bfr[6];
#pragma unroll
        for (int nt = 0; nt < 6; ++nt) bfr[nt] = *(const bf16x8*)&Bs[nh * 96 + nt * 16 + l15][g * 8];
#pragma unroll
        for (int nt = 0; nt < 6; ++nt)
            acc[nt] = __builtin_amdgcn_mfma_f32_16x16x32_bf16(af, bfr[nt], acc[nt], 0, 0, 0);
    }

    float ssp[4] = {0.f, 0.f, 0.f, 0.f};
#pragma unroll
    for (int r2 = 0; r2 < 4; ++r2) {
        const int m = m0 + mt * 16 + g * 4 + r2;
#pragma unroll
        for (int nt = 0; nt < 6; ++nt) {
            const int n = nh * 96 + nt * 16 + l15;
            float rres = RESBF16 ? bf2f(((const unsigned short*)Resp)[(size_t)m * E_ + n])
                                 : ((const float*)Resp)[(size_t)m * E_ + n];
            float v = acc[nt][r2] + rres;
            acc[nt][r2] = v;
            ssp[r2] += v * v;
        }
    }
#pragma unroll
    for (int off = 1; off < 16; off <<= 1)
#pragma unroll
        for (int r2 = 0; r2 < 4; ++r2)
            ssp[r2] += __shfl_xor(ssp[r2], off);
    if (l15 == 0) {
#pragma unroll
        for (int r2 = 0; r2 < 4; ++r2)
            ss_red[w][g * 4 + r2] = ssp[r2];
    }
    __syncthreads();
#pragma unroll
    for (int r2 = 0; r2 < 4; ++r2) {
        const int lr = g * 4 + r2;
        const float ss = ss_red[mt][lr] + ss_red[2 + mt][lr];
        const float inv = rsqrtf(ss * (1.0f / 192.0f) + 1.1920929e-07f);
        const int m = m0 + mt * 16 + lr;
        size_t orow;
        if (EPI == 2) {        // X -> XR
            const int b = m >> 13, rr = (m >> 3) & 1023, gg = m & 7;
            orow = (((size_t)b * G_ + gg) << 10) + rr;
        } else if (EPI == 3) { // XR -> X
            const int b = m >> 13, gg = (m >> 10) & 7, rr = m & 1023;
            orow = ((((size_t)b << 10) + rr) << 3) + gg;
        } else {
            orow = m;
        }
#pragma unroll
        for (int nt = 0; nt < 6; ++nt) {
            const int n = nh * 96 + nt * 16 + l15;
            const float v = acc[nt][r2] * inv * gvec[n];
            if (EPI == 4) ((float*)Cp)[orow * E_ + n] = v;
            else          ((unsigned short*)Cp)[orow * E_ + n] = f2bf(v);
        }
    }
}

// ---- Feature-group attention. QKV fused buffer [M][576]: Q=0, K=+192, V=+384.
__global__ __launch_bounds__(256)
void k_attn1(const unsigned short* __restrict__ QKV, unsigned short* __restrict__ T)
{
    const int wave = blockIdx.x * 4 + (threadIdx.x >> 6);
    const int lane = threadIdx.x & 63;
    const int seq = wave / H_;
    const int h = wave % H_;
    const int i = lane >> 3, j = lane & 7;
    const unsigned short* qp = QKV + ((size_t)(seq * G_ + i)) * 576 + h * D_;
    const unsigned short* kp = QKV + ((size_t)(seq * G_ + j)) * 576 + 192 + h * D_;
    float s = 0.f;
#pragma unroll
    for (int d8 = 0; d8 < 4; ++d8) {
        u16x8 qv = *(const u16x8*)(qp + d8 * 8);
        u16x8 kv = *(const u16x8*)(kp + d8 * 8);
#pragma unroll
        for (int e = 0; e < 8; ++e) s += bf2f(qv[e]) * bf2f(kv[e]);
    }
    float mx = s;
#pragma unroll
    for (int off = 1; off < 8; off <<= 1) mx = fmaxf(mx, __shfl_xor(mx, off));
    float p = __expf(s - mx);
    float sum = p;
#pragma unroll
    for (int off = 1; off < 8; off <<= 1) sum += __shfl_xor(sum, off);
    p /= sum;
    const int base = lane & ~7;
    float o0 = 0.f, o1 = 0.f, o2 = 0.f, o3 = 0.f;
#pragma unroll
    for (int jj = 0; jj < 8; ++jj) {
        float pj = __shfl(p, base + jj);
        ushort4 vv = *(const ushort4*)(QKV + ((size_t)(seq * G_ + jj)) * 576 + 384 + h * D_ + j * 4);
        o0 += pj * bf2f(vv.x); o1 += pj * bf2f(vv.y);
        o2 += pj * bf2f(vv.z); o3 += pj * bf2f(vv.w);
    }
    ushort4 ov; ov.x = f2bf(o0); ov.y = f2bf(o1); ov.z = f2bf(o2); ov.w = f2bf(o3);
    *(ushort4*)(T + ((size_t)(seq * G_ + i)) * E_ + h * D_ + j * 4) = ov;
}

// ---- Row attention, MFMA flash, exp2 domain (log2e folded into Wq2).
// P stays entirely in registers (custom k-order shared by both PV operands);
// V staged in tr-subtile layout ([dg][k/4][4x16]) with ONE b128 write/thread,
// read back via ds_read_b64_tr_b16 (1 addr + 8 compile-time offsets).
// Denominator via ones-row MFMA; defer-max per-lane check (shfls only in the
// rare rescale branch). LDS 9.2 KB.
__global__ __launch_bounds__(256)
void k_attn2(const unsigned short* __restrict__ QKV, unsigned short* __restrict__ T,
             const int* __restrict__ sep_ptr)
{
    __shared__ __align__(16) unsigned short K_lds[64][40];
    __shared__ __align__(16) unsigned short V_lds[2048];   // [dg(2)][kblk(16)][4][16]

    const int sep = *sep_ptr;
    const int bid = blockIdx.x;
    const int sh = ((bid >> 7) << 3) | (bid & 7);   // same (s,h) => same XCD
    const int qtile = (bid >> 3) & 15;
    const int s = sh / H_, h = sh % H_;
    const int q0 = qtile * 64;

    const int tid = threadIdx.x;
    const int w = tid >> 6;
    const int lane = tid & 63;
    const int l15 = lane & 15;
    const int g = lane >> 4;

    const int qrow = q0 + w * 16 + l15;
    u16x8 qf = *(const u16x8*)(QKV + ((size_t)s * R_ + qrow) * 576 + h * D_ + g * 8);

    u16x8 onesu;
#pragma unroll
    for (int e = 0; e < 8; ++e) onesu[e] = 0x3F80;  // bf16 1.0
    const bf16x8 onesf = (bf16x8)onesu;

    const bool lo = (q0 < sep);
    const bool hi = (q0 + 64 > sep);
    const int npass = (lo && hi) ? 2 : 1;
    const int nChunk = (sep + 63) >> 6;

    const int skey = tid >> 2;
    const int sg   = tid & 3;
    // V subtile write slot (elems), constant across chunks
    const int vst = ((sg >> 1) * 16 + (skey >> 2)) * 64 + (skey & 3) * 16 + (sg & 1) * 8;
    // tr-read base byte address (per-lane), constant across chunks
    const unsigned vaddr = (unsigned)(size_t)&V_lds[0] + (unsigned)(g * 128 + l15 * 2);

    for (int pass = 0; pass < npass; ++pass) {
        const int hk = (pass == 0) ? (lo ? h : 0) : 0;
        const unsigned short* Kb = QKV + (size_t)s * R_ * 576 + 192 + hk * D_;
        const unsigned short* Vb = QKV + (size_t)s * R_ * 576 + 384 + hk * D_;

        float mrun = -1e30f;
        f32x4 o0 = {0.f, 0.f, 0.f, 0.f};
        f32x4 o1 = {0.f, 0.f, 0.f, 0.f};
        f32x4 o2 = {0.f, 0.f, 0.f, 0.f};   // ones-row: running sum of P

        // prologue: prefetch chunk 0 into regs
        u16x8 kv_k = *(const u16x8*)(Kb + (size_t)skey * 576 + sg * 8);
        u16x8 kv_v = *(const u16x8*)(Vb + (size_t)skey * 576 + sg * 8);

        for (int kc = 0; kc < nChunk; ++kc) {
            const int kbase = kc * 64;
            const bool full = (kbase + 64 <= sep);
            __syncthreads();
            *(u16x8*)&K_lds[skey][sg * 8] = kv_k;
            *(u16x8*)&V_lds[vst] = kv_v;
            __syncthreads();
            if (kc + 1 < nChunk) {
                kv_k = *(const u16x8*)(Kb + (size_t)(kbase + 64 + skey) * 576 + sg * 8);
                kv_v = *(const u16x8*)(Vb + (size_t)(kbase + 64 + skey) * 576 + sg * 8);
            }

            f32x4 sc[4];
            const f32x4 zf = {0.f, 0.f, 0.f, 0.f};
            __builtin_amdgcn_s_setprio(1);
#pragma unroll
            for (int t = 0; t < 4; ++t) {
                bf16x8 a = *(const bf16x8*)&K_lds[t * 16 + l15][g * 8];
                sc[t] = __builtin_amdgcn_mfma_f32_16x16x32_bf16(a, (bf16x8)qf, zf, 0, 0, 0);
            }
            __builtin_amdgcn_s_setprio(0);
            if (!full) {
#pragma unroll
                for (int t = 0; t < 4; ++t)
#pragma unroll
                    for (int r = 0; r < 4; ++r)
                        if (kbase + t * 16 + g * 4 + r >= sep) sc[t][r] = -1e30f;
            }
            // per-lane max over this lane's 16 scores (max3-fusable)
            float mx = fmaxf(fmaxf(sc[0][0], sc[0][1]), sc[0][2]);
            mx = fmaxf(fmaxf(sc[0][3], sc[1][0]), mx);
            mx = fmaxf(fmaxf(sc[1][1], sc[1][2]), mx);
            mx = fmaxf(fmaxf(sc[1][3], sc[2][0]), mx);
            mx = fmaxf(fmaxf(sc[2][1], sc[2][2]), mx);
            mx = fmaxf(fmaxf(sc[2][3], sc[3][0]), mx);
            mx = fmaxf(fmaxf(sc[3][1], sc[3][2]), mx);
            mx = fmaxf(mx, sc[3][3]);
            // defer-max: cross-lane reduction only in the rare rescale branch
            if (!__all((int)(mx <= mrun + 11.0f))) {
                mx = fmaxf(mx, __shfl_xor(mx, 16));
                mx = fmaxf(mx, __shfl_xor(mx, 32));
                const float mnew = fmaxf(mrun, mx);
                const float scl = exp2f(mrun - mnew);
#pragma unroll
                for (int r = 0; r < 4; ++r) { o0[r] *= scl; o1[r] *= scl; o2[r] *= scl; }
                mrun = mnew;
            }
            // P -> B-fragments in registers (k-order: e<4 -> key ks*32+g*4+e,
            // e>=4 -> key ks*32+16+g*4+(e-4); matches the tr-read V order)
            bf16x8 pb0, pb1;
            {
                u16x8 p0, p1;
#pragma unroll
                for (int r = 0; r < 4; ++r) {
                    p0[r]     = f2bf(exp2f(sc[0][r] - mrun));
                    p0[4 + r] = f2bf(exp2f(sc[1][r] - mrun));
                    p1[r]     = f2bf(exp2f(sc[2][r] - mrun));
                    p1[4 + r] = f2bf(exp2f(sc[3][r] - mrun));
                }
                pb0 = (bf16x8)p0; pb1 = (bf16x8)p1;
            }
            // V^T fragments via hardware transpose reads (offset = dg*2048+ks*1024+h*512)
            unsigned long long t0, t1, t2, t3, t4, t5, t6, t7;
            asm volatile(
                "ds_read_b64_tr_b16 %0, %8 offset:0\n\t"
                "ds_read_b64_tr_b16 %1, %8 offset:512\n\t"
                "ds_read_b64_tr_b16 %2, %8 offset:1024\n\t"
                "ds_read_b64_tr_b16 %3, %8 offset:1536\n\t"
                "ds_read_b64_tr_b16 %4, %8 offset:2048\n\t"
                "ds_read_b64_tr_b16 %5, %8 offset:2560\n\t"
                "ds_read_b64_tr_b16 %6, %8 offset:3072\n\t"
                "ds_read_b64_tr_b16 %7, %8 offset:3584\n\t"
                "s_waitcnt lgkmcnt(0)"
                : "=&v"(t0), "=&v"(t1), "=&v"(t2), "=&v"(t3),
                  "=&v"(t4), "=&v"(t5), "=&v"(t6), "=&v"(t7)
                : "v"(vaddr)
                : "memory");
            __builtin_amdgcn_sched_barrier(0);
            __builtin_amdgcn_s_setprio(1);
            o0 = __builtin_amdgcn_mfma_f32_16x16x32_bf16(mk8(t0, t1), pb0, o0, 0, 0, 0);
            o1 = __builtin_amdgcn_mfma_f32_16x16x32_bf16(mk8(t4, t5), pb0, o1, 0, 0, 0);
            o2 = __builtin_amdgcn_mfma_f32_16x16x32_bf16(onesf,       pb0, o2, 0, 0, 0);
            o0 = __builtin_amdgcn_mfma_f32_16x16x32_bf16(mk8(t2, t3), pb1, o0, 0, 0, 0);
            o1 = __builtin_amdgcn_mfma_f32_16x16x32_bf16(mk8(t6, t7), pb1, o1, 0, 0, 0);
            o2 = __builtin_amdgcn_mfma_f32_16x16x32_bf16(onesf,       pb1, o2, 0, 0, 0);
            __builtin_amdgcn_s_setprio(0);
        }

        const bool valid = (npass == 1) || (pass == 0 ? (qrow < sep) : (qrow >= sep));
        if (valid) {
            const float inv = 1.f / o2[0];   // sum_k P[q][k]
            unsigned short* tp = T + ((size_t)s * R_ + qrow) * E_ + h * D_;
            ushort4 v0, v1;
            v0.x = f2bf(o0[0] * inv); v0.y = f2bf(o0[1] * inv);
            v0.z = f2bf(o0[2] * inv); v0.w = f2bf(o0[3] * inv);
            v1.x = f2bf(o1[0] * inv); v1.y = f2bf(o1[1] * inv);
            v1.z = f2bf(o1[2] * inv); v1.w = f2bf(o1[3] * inv);
            *(ushort4*)(tp + g * 4)      = v0;
            *(ushort4*)(tp + 16 + g * 4) = v1;
        }
    }
}

extern "C" void kernel_launch(void* const* d_in, const int* in_sizes, int n_in,
                              void* d_out, int out_size, void* d_ws, size_t ws_size,
                              hipStream_t stream) {
    const float* hidden = (const float*)d_in[0];
    const float* Wq1 = (const float*)d_in[1];
    const float* Wk1 = (const float*)d_in[2];
    const float* Wv1 = (const float*)d_in[3];
    const float* Wo1 = (const float*)d_in[4];
    const float* Wq2 = (const float*)d_in[5];
    const float* Wk2 = (const float*)d_in[6];
    const float* Wv2 = (const float*)d_in[7];
    const float* Wo2 = (const float*)d_in[8];
    const float* W1  = (const float*)d_in[9];
    const float* W2  = (const float*)d_in[10];
    const float* g1  = (const float*)d_in[11];
    const float* g2  = (const float*)d_in[12];
    const float* g3  = (const float*)d_in[13];
    const int*   sep = (const int*)d_in[14];

    float* Xout = (float*)d_out;                    // final f32 X-layout output
    unsigned short* ws = (unsigned short*)d_ws;
    unsigned short* QKVb = ws;                      // [M][576] bf16 (aliases H1 [M][384])
    unsigned short* Tb   = QKVb + (size_t)M_ * 576;
    unsigned short* Ynb  = Tb + NBUF;               // rms-g1 output, XR layout
    unsigned short* Xcb  = Ynb + NBUF;              // rms-g2 output, X layout
    unsigned short* Xb   = Xcb + NBUF;              // inter-layer residual (layers 0-2)
    unsigned short* Wt   = Xb + NBUF;
    unsigned short* H1b  = QKVb;

    const dim3 blk(256);
    const dim3 gQKV(M_ / 64, 3);
    const dim3 gW1(M_ / 64, 2);
    const dim3 g32(M_ / 32);                        // rms-GEMM: 1024 blocks, 4/CU
    const dim3 gA1((4096 * H_) / 4);
    const dim3 gA2(32 * H_ * 16);

    k_convw_all<<<dim3(432 * L_), blk, 0, stream>>>(Wq1, Wk1, Wv1, Wo1, Wq2, Wk2, Wv2, Wo2, W1, W2, Wt);

    for (int i = 0; i < L_; ++i) {
        unsigned short* wl = Wt + (size_t)i * WPL;
        const unsigned short* wqkv1 = wl;
        const unsigned short* wo1   = wl + 3 * (size_t)E_ * E_;
        const unsigned short* wqkv2 = wl + 4 * (size_t)E_ * E_;
        const unsigned short* wo2   = wl + 7 * (size_t)E_ * E_;
        const unsigned short* w1    = wl + 8 * (size_t)E_ * E_;
        const unsigned short* w2    = wl + 8 * (size_t)E_ * E_ + (size_t)E_ * F_;
        const float* g1i = g1 + (size_t)i * E_;
        const float* g2i = g2 + (size_t)i * E_;
        const float* g3i = g3 + (size_t)i * E_;

        // --- feature-group attention block ---
        if (i == 0)
            k_gemm_mfma<false, 0><<<gQKV, blk, 0, stream>>>(hidden, wqkv1, QKVb, 576, E_);
        else
            k_gemm_mfma<true, 0><<<gQKV, blk, 0, stream>>>(Xb, wqkv1, QKVb, 576, E_);
        k_attn1<<<gA1, blk, 0, stream>>>(QKVb, Tb);
        if (i == 0)
            k_gemm_rms32<false, 2><<<g32, blk, 0, stream>>>(Tb, wo1, hidden, g1i, Ynb, E_);
        else
            k_gemm_rms32<true, 2><<<g32, blk, 0, stream>>>(Tb, wo1, Xb, g1i, Ynb, E_);
        // --- row attention block ---
        k_gemm_mfma<true, 0><<<gQKV, blk, 0, stream>>>(Ynb, wqkv2, QKVb, 576, E_);
        k_attn2<<<gA2, blk, 0, stream>>>(QKVb, Tb, sep);
        k_gemm_rms32<true, 3><<<g32, blk, 0, stream>>>(Tb, wo2, Ynb, g2i, Xcb, E_);
        // --- MLP block ---
        k_gemm_mfma<true, 1><<<gW1, blk, 0, stream>>>(Xcb, w1, H1b, F_, E_);
        if (i == L_ - 1)
            k_gemm_rms32<true, 4><<<g32, blk, 0, stream>>>(H1b, w2, Xcb, g3i, Xout, F_);
        else
            k_gemm_rms32<true, 5><<<g32, blk, 0, stream>>>(H1b, w2, Xcb, g3i, Xb, F_);
    }
}